// Round 2
// baseline (276.588 us; speedup 1.0000x reference)
//
#include <hip/hip_runtime.h>
#include <hip/hip_bf16.h>
#include <math.h>

#define NEG_SLOPE 0.2f

constexpr int BSZ = 8, T = 100, NN = 2048, N = BSZ * NN; // N = 16384
constexpr int CIN = 128, H1 = 4, C1 = 64, F1 = 256, F2 = 128;
constexpr int E = 32768;

__device__ inline void fma4(float4& a, float s, const float4& w) {
    a.x = fmaf(s, w.x, a.x); a.y = fmaf(s, w.y, a.y);
    a.z = fmaf(s, w.z, a.z); a.w = fmaf(s, w.w, a.w);
}

// K1: x[N,128] = input^T(b,node,t) @ W_temb + b_temb. 32 node-rows per block.
__global__ __launch_bounds__(256) void k_temb(const float* __restrict__ in,
        const float* __restrict__ Wt, const float* __restrict__ bt,
        float* __restrict__ x) {
    const int ROWS = 32, STR = ROWS + 4;
    alignas(16) __shared__ float xT[T * STR];
    int t = threadIdx.x;
    int row0 = blockIdx.x * ROWS;
    int b = row0 / NN;
    int node0 = row0 % NN;
    for (int i = t; i < T * ROWS; i += 256) {
        int tk = i >> 5, r = i & 31;
        xT[tk * STR + r] = in[(b * T + tk) * NN + node0 + r];
    }
    __syncthreads();
    int cg = t & 31;   // cols 4cg..4cg+3
    int rg = t >> 5;   // rows rg*4..rg*4+3
    float4 acc[4] = {{0,0,0,0},{0,0,0,0},{0,0,0,0},{0,0,0,0}};
    #pragma unroll 2
    for (int k = 0; k < T; ++k) {
        float4 w  = *(const float4*)&Wt[k * CIN + 4 * cg];
        float4 xv = *(const float4*)&xT[k * STR + rg * 4];
        fma4(acc[0], xv.x, w); fma4(acc[1], xv.y, w);
        fma4(acc[2], xv.z, w); fma4(acc[3], xv.w, w);
    }
    float4 bv = *(const float4*)&bt[4 * cg];
    #pragma unroll
    for (int r = 0; r < 4; ++r) {
        float4 o = acc[r];
        o.x += bv.x; o.y += bv.y; o.z += bv.z; o.w += bv.w;
        *(float4*)&x[(row0 + rg * 4 + r) * CIN + 4 * cg] = o;
    }
}

// Dual GEMM: outL = X@Wl, outR = X@Wr.  X:[*,KD] row-major, W:[KD,COLS].
template<int KD, int COLS, int ROWS>
__global__ __launch_bounds__(256) void k_gemm2(const float* __restrict__ X,
        const float* __restrict__ Wl, const float* __restrict__ Wr,
        float* __restrict__ outL, float* __restrict__ outR) {
    const int STR = ROWS + 4;
    const int CG = COLS / 4;
    alignas(16) __shared__ float xT[KD * STR];
    int t = threadIdx.x;
    int row0 = blockIdx.x * ROWS;
    for (int i = t; i < ROWS * (KD / 4); i += 256) {
        int r = i / (KD / 4), kq = i % (KD / 4);
        float4 v = *(const float4*)&X[(row0 + r) * KD + 4 * kq];
        xT[(4 * kq + 0) * STR + r] = v.x;
        xT[(4 * kq + 1) * STR + r] = v.y;
        xT[(4 * kq + 2) * STR + r] = v.z;
        xT[(4 * kq + 3) * STR + r] = v.w;
    }
    __syncthreads();
    int cg = t % CG;
    int rg = t / CG;
    float4 aL[4] = {{0,0,0,0},{0,0,0,0},{0,0,0,0},{0,0,0,0}};
    float4 aR[4] = {{0,0,0,0},{0,0,0,0},{0,0,0,0},{0,0,0,0}};
    #pragma unroll 4
    for (int k = 0; k < KD; ++k) {
        float4 wl = *(const float4*)&Wl[k * COLS + 4 * cg];
        float4 wr = *(const float4*)&Wr[k * COLS + 4 * cg];
        float4 xv = *(const float4*)&xT[k * STR + rg * 4];
        fma4(aL[0], xv.x, wl); fma4(aR[0], xv.x, wr);
        fma4(aL[1], xv.y, wl); fma4(aR[1], xv.y, wr);
        fma4(aL[2], xv.z, wl); fma4(aR[2], xv.z, wr);
        fma4(aL[3], xv.w, wl); fma4(aR[3], xv.w, wr);
    }
    #pragma unroll
    for (int r = 0; r < 4; ++r) {
        *(float4*)&outL[(row0 + rg * 4 + r) * COLS + 4 * cg] = aL[r];
        *(float4*)&outR[(row0 + rg * 4 + r) * COLS + 4 * cg] = aR[r];
    }
}

// K3: self-loop logits layer1 + init denom/accum. One block per node.
__global__ __launch_bounds__(256) void k_self1(const float* __restrict__ xl,
        const float* __restrict__ xr, const float* __restrict__ att,
        float* __restrict__ s1, float* __restrict__ dn, float* __restrict__ accum) {
    int d = blockIdx.x;
    int f = threadIdx.x;
    float a = xl[d * F1 + f], b = xr[d * F1 + f];
    float m = a + b; m = m > 0.f ? m : NEG_SLOPE * m;
    float p = m * att[f];
    for (int off = 32; off; off >>= 1) p += __shfl_xor(p, off, 64);
    accum[d * F1 + f] = a;
    if ((f & 63) == 0) {
        s1[d * H1 + (f >> 6)] = p;
        dn[d * H1 + (f >> 6)] = 1.0f;
    }
}

// K4: unique edges with multiplicity 8, layer1. One block per edge.
__global__ __launch_bounds__(256) void k_edge1(const int* __restrict__ ei,
        const float* __restrict__ xl, const float* __restrict__ xr,
        const float* __restrict__ att, const float* __restrict__ s1,
        float* __restrict__ dn, float* __restrict__ accum) {
    int e = blockIdx.x;
    int s = ei[e], d = ei[E + e];
    int f = threadIdx.x;
    float a = xl[s * F1 + f], b = xr[d * F1 + f];
    float m = a + b; m = m > 0.f ? m : NEG_SLOPE * m;
    float p = m * att[f];
    for (int off = 32; off; off >>= 1) p += __shfl_xor(p, off, 64);
    int h = f >> 6;
    float w = 8.0f * __expf(p - s1[d * H1 + h]);
    if ((f & 63) == 0) atomicAdd(&dn[d * H1 + h], w);
    atomicAdd(&accum[d * F1 + f], w * a);
}

// K5: h1 = elu(accum/denom + b1), in place. One float4 per thread.
__global__ __launch_bounds__(256) void k_fin1(const float* __restrict__ dn,
        const float* __restrict__ b1, float* __restrict__ accum) {
    int idx = blockIdx.x * 256 + threadIdx.x;
    float4 v = *(float4*)&accum[idx * 4];
    int f = (idx * 4) % F1;
    int node = (idx * 4) / F1;
    float d = dn[node * H1 + (f >> 6)] + 1e-16f;
    float4 bv = *(const float4*)&b1[f];
    v.x = v.x / d + bv.x; v.y = v.y / d + bv.y;
    v.z = v.z / d + bv.z; v.w = v.w / d + bv.w;
    v.x = v.x > 0.f ? v.x : expm1f(v.x);
    v.y = v.y > 0.f ? v.y : expm1f(v.y);
    v.z = v.z > 0.f ? v.z : expm1f(v.z);
    v.w = v.w > 0.f ? v.w : expm1f(v.w);
    *(float4*)&accum[idx * 4] = v;
}

// K7: self-loop logits layer2 (H=1, C=128). 4 nodes per block, 64 lanes/node.
__global__ __launch_bounds__(256) void k_self2(const float* __restrict__ xl,
        const float* __restrict__ xr, const float* __restrict__ att,
        float* __restrict__ s2, float* __restrict__ dn, float* __restrict__ accum) {
    int node = blockIdx.x * 4 + (threadIdx.x >> 6);
    int c = threadIdx.x & 63;
    float a0 = xl[node * F2 + c], a1 = xl[node * F2 + c + 64];
    float b0 = xr[node * F2 + c], b1 = xr[node * F2 + c + 64];
    float m0 = a0 + b0; m0 = m0 > 0.f ? m0 : NEG_SLOPE * m0;
    float m1 = a1 + b1; m1 = m1 > 0.f ? m1 : NEG_SLOPE * m1;
    float p = m0 * att[c] + m1 * att[c + 64];
    for (int off = 32; off; off >>= 1) p += __shfl_xor(p, off, 64);
    accum[node * F2 + c] = a0;
    accum[node * F2 + c + 64] = a1;
    if (c == 0) { s2[node] = p; dn[node] = 1.0f; }
}

// K8: unique edges, layer2. 4 edges per block.
__global__ __launch_bounds__(256) void k_edge2(const int* __restrict__ ei,
        const float* __restrict__ xl, const float* __restrict__ xr,
        const float* __restrict__ att, const float* __restrict__ s2,
        float* __restrict__ dn, float* __restrict__ accum) {
    int e = blockIdx.x * 4 + (threadIdx.x >> 6);
    int s = ei[e], d = ei[E + e];
    int c = threadIdx.x & 63;
    float a0 = xl[s * F2 + c], a1 = xl[s * F2 + c + 64];
    float b0 = xr[d * F2 + c], b1 = xr[d * F2 + c + 64];
    float m0 = a0 + b0; m0 = m0 > 0.f ? m0 : NEG_SLOPE * m0;
    float m1 = a1 + b1; m1 = m1 > 0.f ? m1 : NEG_SLOPE * m1;
    float p = m0 * att[c] + m1 * att[c + 64];
    for (int off = 32; off; off >>= 1) p += __shfl_xor(p, off, 64);
    float w = 8.0f * __expf(p - s2[d]);
    if (c == 0) atomicAdd(&dn[d], w);
    atomicAdd(&accum[d * F2 + c], w * a0);
    atomicAdd(&accum[d * F2 + c + 64], w * a1);
}

// K9: out[b,c] = mean over nodes of (accum/denom) + b2. 16 node-chunks per batch.
__global__ __launch_bounds__(128) void k_out(const float* __restrict__ accum,
        const float* __restrict__ dn, const float* __restrict__ b2,
        float* __restrict__ out) {
    int b = blockIdx.x, chunk = blockIdx.y;
    int c = threadIdx.x;
    float acc = 0.f;
    int n0 = b * NN + chunk * 128;
    for (int i = 0; i < 128; ++i) {
        int node = n0 + i;
        acc += accum[node * F2 + c] / (dn[node] + 1e-16f);
    }
    float val = acc * (1.0f / NN);
    if (chunk == 0) val += b2[c];
    atomicAdd(&out[b * F2 + c], val);
}

extern "C" void kernel_launch(void* const* d_in, const int* in_sizes, int n_in,
                              void* d_out, int out_size, void* d_ws, size_t ws_size,
                              hipStream_t stream) {
    const float* in   = (const float*)d_in[0];
    const int*   ei   = (const int*)d_in[1];
    const float* Wt   = (const float*)d_in[2];
    const float* bt   = (const float*)d_in[3];
    const float* Wl1  = (const float*)d_in[4];
    const float* Wr1  = (const float*)d_in[5];
    const float* att1 = (const float*)d_in[6];
    const float* b1   = (const float*)d_in[7];
    const float* Wl2  = (const float*)d_in[8];
    const float* Wr2  = (const float*)d_in[9];
    const float* att2 = (const float*)d_in[10];
    const float* b2   = (const float*)d_in[11];
    float* out = (float*)d_out;

    float* ws   = (float*)d_ws;
    float* x    = ws;                 // N*CIN = 2,097,152
    float* xl1  = x   + N * CIN;      // N*F1  = 4,194,304
    float* xr1  = xl1 + N * F1;      // N*F1
    float* acc1 = xr1 + N * F1;      // N*F1  (becomes h1 in place)
    float* s1   = acc1 + N * F1;     // N*H1
    float* dn1  = s1 + N * H1;       // N*H1
    float* s2   = dn1 + N * H1;      // N
    float* dn2  = s2 + N;            // N
    // reuse: x dead after gemm1; xr1 region reused for xl2/acc2
    float* xl2  = x;                  // N*F2
    float* xr2  = xr1;                // N*F2
    float* acc2 = xr1 + N * F2;       // N*F2 (within xr1's N*F1 allocation)

    hipMemsetAsync(d_out, 0, (size_t)out_size * sizeof(float), stream);

    k_temb<<<N / 32, 256, 0, stream>>>(in, Wt, bt, x);
    k_gemm2<CIN, F1, 16><<<N / 16, 256, 0, stream>>>(x, Wl1, Wr1, xl1, xr1);
    k_self1<<<N, 256, 0, stream>>>(xl1, xr1, att1, s1, dn1, acc1);
    k_edge1<<<E, 256, 0, stream>>>(ei, xl1, xr1, att1, s1, dn1, acc1);
    k_fin1<<<N * F1 / 1024, 256, 0, stream>>>(dn1, b1, acc1);
    k_gemm2<F1, F2, 32><<<N / 32, 256, 0, stream>>>(acc1, Wl2, Wr2, xl2, xr2);
    k_self2<<<N / 4, 256, 0, stream>>>(xl2, xr2, att2, s2, dn2, acc2);
    k_edge2<<<E / 4, 256, 0, stream>>>(ei, xl2, xr2, att2, s2, dn2, acc2);
    k_out<<<dim3(BSZ, 16), 128, 0, stream>>>(acc2, dn2, b2, out);
}

// Round 3
// 227.137 us; speedup vs baseline: 1.2177x; 1.2177x over previous
//
#include <hip/hip_runtime.h>
#include <hip/hip_bf16.h>
#include <math.h>

#define NEG_SLOPE 0.2f

constexpr int BSZ = 8, T = 100, NN = 2048, N = BSZ * NN; // N = 16384
constexpr int CIN = 128, H1 = 4, F1 = 256, F2 = 128;
constexpr int E = 32768;

__device__ inline void fma4(float4& a, float s, const float4& w) {
    a.x = fmaf(s, w.x, a.x); a.y = fmaf(s, w.y, a.y);
    a.z = fmaf(s, w.z, a.z); a.w = fmaf(s, w.w, a.w);
}
__device__ inline float4 z4() { return make_float4(0.f, 0.f, 0.f, 0.f); }
__device__ inline float lrelu(float m) { return m > 0.f ? m : NEG_SLOPE * m; }
__device__ inline float eluf(float v) { return v > 0.f ? v : expm1f(v); }
// sum_j lrelu(a_j + b_j) * att_j
__device__ inline float ldot(const float4& a, const float4& b, const float4& at) {
    return lrelu(a.x + b.x) * at.x + lrelu(a.y + b.y) * at.y +
           lrelu(a.z + b.z) * at.z + lrelu(a.w + b.w) * at.w;
}

// K1: x[N,128] = input^T @ W_temb + b_temb. 32 rows/block, weights in LDS.
__global__ __launch_bounds__(256) void k_temb(const float* __restrict__ in,
        const float* __restrict__ Wt, const float* __restrict__ bt,
        float* __restrict__ x) {
    constexpr int STR = 36;
    alignas(16) __shared__ float xs[T * STR];    // 14.4 KB
    alignas(16) __shared__ float ws[T * CIN];    // 51.2 KB
    const int t = threadIdx.x;
    const int tc = t & 31, tr = t >> 5;
    const int row0 = blockIdx.x * 32;
    const int b = row0 / NN, node0 = row0 % NN;
    for (int i = t; i < T * 32; i += 256) {
        int tk = i >> 5, r = i & 31;
        xs[tk * STR + r] = in[(b * T + tk) * NN + node0 + r];
    }
    for (int i = t; i < T * CIN / 4; i += 256)
        ((float4*)ws)[i] = ((const float4*)Wt)[i];
    __syncthreads();
    float4 acc[4] = {z4(), z4(), z4(), z4()};
    #pragma unroll 4
    for (int k = 0; k < T; ++k) {
        float4 xv = *(const float4*)&xs[k * STR + tr * 4];
        float4 wv = *(const float4*)&ws[k * CIN + tc * 4];
        fma4(acc[0], xv.x, wv); fma4(acc[1], xv.y, wv);
        fma4(acc[2], xv.z, wv); fma4(acc[3], xv.w, wv);
    }
    float4 bv = *(const float4*)&bt[tc * 4];
    #pragma unroll
    for (int r = 0; r < 4; ++r) {
        float4 o = acc[r];
        o.x += bv.x; o.y += bv.y; o.z += bv.z; o.w += bv.w;
        *(float4*)&x[(row0 + tr * 4 + r) * CIN + tc * 4] = o;
    }
}

// G1: layer-1 dual GEMM (K=128 -> 256 cols) + fused self-logit / dn / accum init.
__global__ __launch_bounds__(256) void g1(const float* __restrict__ X,
        const float* __restrict__ Wl, const float* __restrict__ Wr,
        const float* __restrict__ att,
        float* __restrict__ xl, float* __restrict__ xr,
        float* __restrict__ acc1, float* __restrict__ s1, float* __restrict__ dn1) {
    constexpr int KT = 32, STR = 36;
    alignas(16) __shared__ float xs[KT * STR];    // 4.6 KB
    alignas(16) __shared__ float wls[KT * F1];    // 32 KB
    alignas(16) __shared__ float wrs[KT * F1];    // 32 KB
    const int t = threadIdx.x;
    const int tc = t & 31, tr = t >> 5;
    const int row0 = blockIdx.x * 32;
    float4 aL0[4] = {z4(), z4(), z4(), z4()}, aL1[4] = {z4(), z4(), z4(), z4()};
    float4 aR0[4] = {z4(), z4(), z4(), z4()}, aR1[4] = {z4(), z4(), z4(), z4()};
    for (int kt = 0; kt < CIN; kt += KT) {
        __syncthreads();
        {   // stage x^T tile: 32 rows x 32 k
            int r = t >> 3, kq = t & 7;
            float4 v = *(const float4*)&X[(row0 + r) * CIN + kt + kq * 4];
            xs[(4 * kq + 0) * STR + r] = v.x;
            xs[(4 * kq + 1) * STR + r] = v.y;
            xs[(4 * kq + 2) * STR + r] = v.z;
            xs[(4 * kq + 3) * STR + r] = v.w;
        }
        #pragma unroll
        for (int it = 0; it < 8; ++it) {  // stage 32x256 weight tiles
            int idx = t + it * 256;
            int kk = idx >> 6, c4 = idx & 63;
            *(float4*)&wls[kk * F1 + c4 * 4] = *(const float4*)&Wl[(kt + kk) * F1 + c4 * 4];
            *(float4*)&wrs[kk * F1 + c4 * 4] = *(const float4*)&Wr[(kt + kk) * F1 + c4 * 4];
        }
        __syncthreads();
        #pragma unroll 4
        for (int kk = 0; kk < KT; ++kk) {
            float4 xv  = *(const float4*)&xs[kk * STR + tr * 4];
            float4 wl0 = *(const float4*)&wls[kk * F1 + tc * 4];
            float4 wl1 = *(const float4*)&wls[kk * F1 + 128 + tc * 4];
            float4 wr0 = *(const float4*)&wrs[kk * F1 + tc * 4];
            float4 wr1 = *(const float4*)&wrs[kk * F1 + 128 + tc * 4];
            fma4(aL0[0], xv.x, wl0); fma4(aL1[0], xv.x, wl1);
            fma4(aR0[0], xv.x, wr0); fma4(aR1[0], xv.x, wr1);
            fma4(aL0[1], xv.y, wl0); fma4(aL1[1], xv.y, wl1);
            fma4(aR0[1], xv.y, wr0); fma4(aR1[1], xv.y, wr1);
            fma4(aL0[2], xv.z, wl0); fma4(aL1[2], xv.z, wl1);
            fma4(aR0[2], xv.z, wr0); fma4(aR1[2], xv.z, wr1);
            fma4(aL0[3], xv.w, wl0); fma4(aL1[3], xv.w, wl1);
            fma4(aR0[3], xv.w, wr0); fma4(aR1[3], xv.w, wr1);
        }
    }
    float4 at0 = *(const float4*)&att[tc * 4];
    float4 at1 = *(const float4*)&att[128 + tc * 4];
    #pragma unroll
    for (int r = 0; r < 4; ++r) {
        int row = row0 + tr * 4 + r;
        *(float4*)&xl[row * F1 + tc * 4]         = aL0[r];
        *(float4*)&xl[row * F1 + 128 + tc * 4]   = aL1[r];
        *(float4*)&xr[row * F1 + tc * 4]         = aR0[r];
        *(float4*)&xr[row * F1 + 128 + tc * 4]   = aR1[r];
        *(float4*)&acc1[row * F1 + tc * 4]       = aL0[r];
        *(float4*)&acc1[row * F1 + 128 + tc * 4] = aL1[r];
        float p0 = ldot(aL0[r], aR0[r], at0);   // heads 0/1 (by tc group)
        float p1 = ldot(aL1[r], aR1[r], at1);   // heads 2/3
        #pragma unroll
        for (int off = 8; off; off >>= 1) {     // reduce within 16-lane groups
            p0 += __shfl_xor(p0, off, 64);
            p1 += __shfl_xor(p1, off, 64);
        }
        if ((tc & 15) == 0) {
            int h = tc >> 4;
            s1[row * H1 + h]      = p0;
            s1[row * H1 + 2 + h]  = p1;
            dn1[row * H1 + h]     = 1.0f;
            dn1[row * H1 + 2 + h] = 1.0f;
        }
    }
}

// K4: unique edges with multiplicity 8, layer1. One block per edge.
__global__ __launch_bounds__(256) void k_edge1(const int* __restrict__ ei,
        const float* __restrict__ xl, const float* __restrict__ xr,
        const float* __restrict__ att, const float* __restrict__ s1,
        float* __restrict__ dn, float* __restrict__ accum) {
    int e = blockIdx.x;
    int s = ei[e], d = ei[E + e];
    int f = threadIdx.x;
    float a = xl[s * F1 + f], b = xr[d * F1 + f];
    float p = lrelu(a + b) * att[f];
    for (int off = 32; off; off >>= 1) p += __shfl_xor(p, off, 64);
    int h = f >> 6;
    float w = 8.0f * __expf(p - s1[d * H1 + h]);
    if ((f & 63) == 0) atomicAdd(&dn[d * H1 + h], w);
    atomicAdd(&accum[d * F1 + f], w * a);
}

// G2: layer-2 dual GEMM (K=256 -> 128 cols), fin1 fused into staging,
// self-logit fused into epilogue.
__global__ __launch_bounds__(256) void g2(const float* __restrict__ A1,
        const float* __restrict__ dn1, const float* __restrict__ b1,
        const float* __restrict__ Wl, const float* __restrict__ Wr,
        const float* __restrict__ att,
        float* __restrict__ xl2, float* __restrict__ xr2,
        float* __restrict__ acc2, float* __restrict__ s2, float* __restrict__ dn2) {
    constexpr int KT = 32, STR = 36;
    alignas(16) __shared__ float xs[KT * STR];    // 4.6 KB
    alignas(16) __shared__ float wls[KT * F2];    // 16 KB
    alignas(16) __shared__ float wrs[KT * F2];    // 16 KB
    const int t = threadIdx.x;
    const int tc = t & 31, tr = t >> 5;
    const int row0 = blockIdx.x * 32;
    float4 aL[4] = {z4(), z4(), z4(), z4()}, aR[4] = {z4(), z4(), z4(), z4()};
    for (int kt = 0; kt < F1; kt += KT) {
        __syncthreads();
        {   // stage h1 tile with fused (divide, bias, ELU)
            int r = t >> 3, kq = t & 7;
            int node = row0 + r, col = kt + kq * 4;
            float4 v = *(const float4*)&A1[node * F1 + col];
            float rd = 1.0f / (dn1[node * H1 + (col >> 6)] + 1e-16f);
            float4 bv = *(const float4*)&b1[col];
            v.x = eluf(v.x * rd + bv.x); v.y = eluf(v.y * rd + bv.y);
            v.z = eluf(v.z * rd + bv.z); v.w = eluf(v.w * rd + bv.w);
            xs[(4 * kq + 0) * STR + r] = v.x;
            xs[(4 * kq + 1) * STR + r] = v.y;
            xs[(4 * kq + 2) * STR + r] = v.z;
            xs[(4 * kq + 3) * STR + r] = v.w;
        }
        #pragma unroll
        for (int it = 0; it < 4; ++it) {  // stage 32x128 weight tiles
            int idx = t + it * 256;
            int kk = idx >> 5, c4 = idx & 31;
            *(float4*)&wls[kk * F2 + c4 * 4] = *(const float4*)&Wl[(kt + kk) * F2 + c4 * 4];
            *(float4*)&wrs[kk * F2 + c4 * 4] = *(const float4*)&Wr[(kt + kk) * F2 + c4 * 4];
        }
        __syncthreads();
        #pragma unroll 4
        for (int kk = 0; kk < KT; ++kk) {
            float4 xv = *(const float4*)&xs[kk * STR + tr * 4];
            float4 wl = *(const float4*)&wls[kk * F2 + tc * 4];
            float4 wr = *(const float4*)&wrs[kk * F2 + tc * 4];
            fma4(aL[0], xv.x, wl); fma4(aR[0], xv.x, wr);
            fma4(aL[1], xv.y, wl); fma4(aR[1], xv.y, wr);
            fma4(aL[2], xv.z, wl); fma4(aR[2], xv.z, wr);
            fma4(aL[3], xv.w, wl); fma4(aR[3], xv.w, wr);
        }
    }
    float4 av = *(const float4*)&att[tc * 4];
    #pragma unroll
    for (int r = 0; r < 4; ++r) {
        int row = row0 + tr * 4 + r;
        *(float4*)&xl2[row * F2 + tc * 4]  = aL[r];
        *(float4*)&xr2[row * F2 + tc * 4]  = aR[r];
        *(float4*)&acc2[row * F2 + tc * 4] = aL[r];
        float p = ldot(aL[r], aR[r], av);
        #pragma unroll
        for (int off = 16; off; off >>= 1) p += __shfl_xor(p, off, 64);
        if (tc == 0) { s2[row] = p; dn2[row] = 1.0f; }
    }
}

// K8: unique edges, layer2. 4 edges per block.
__global__ __launch_bounds__(256) void k_edge2(const int* __restrict__ ei,
        const float* __restrict__ xl, const float* __restrict__ xr,
        const float* __restrict__ att, const float* __restrict__ s2,
        float* __restrict__ dn, float* __restrict__ accum) {
    int e = blockIdx.x * 4 + (threadIdx.x >> 6);
    int s = ei[e], d = ei[E + e];
    int c = threadIdx.x & 63;
    float a0 = xl[s * F2 + c], a1 = xl[s * F2 + c + 64];
    float b0 = xr[d * F2 + c], b1 = xr[d * F2 + c + 64];
    float p = lrelu(a0 + b0) * att[c] + lrelu(a1 + b1) * att[c + 64];
    for (int off = 32; off; off >>= 1) p += __shfl_xor(p, off, 64);
    float w = 8.0f * __expf(p - s2[d]);
    if (c == 0) atomicAdd(&dn[d], w);
    atomicAdd(&accum[d * F2 + c], w * a0);
    atomicAdd(&accum[d * F2 + c + 64], w * a1);
}

// K9: out[b,c] = mean over nodes of (accum/denom) + b2. 64 chunks of 32 nodes.
__global__ __launch_bounds__(128) void k_out(const float* __restrict__ accum,
        const float* __restrict__ dn, const float* __restrict__ b2,
        float* __restrict__ out) {
    int b = blockIdx.x, chunk = blockIdx.y;
    int c = threadIdx.x;
    float acc = 0.f;
    int n0 = b * NN + chunk * 32;
    for (int i = 0; i < 32; ++i) {
        int node = n0 + i;
        acc += accum[node * F2 + c] / (dn[node] + 1e-16f);
    }
    float val = acc * (1.0f / NN);
    if (chunk == 0) val += b2[c];
    atomicAdd(&out[b * F2 + c], val);
}

extern "C" void kernel_launch(void* const* d_in, const int* in_sizes, int n_in,
                              void* d_out, int out_size, void* d_ws, size_t ws_size,
                              hipStream_t stream) {
    const float* in   = (const float*)d_in[0];
    const int*   ei   = (const int*)d_in[1];
    const float* Wt   = (const float*)d_in[2];
    const float* bt   = (const float*)d_in[3];
    const float* Wl1  = (const float*)d_in[4];
    const float* Wr1  = (const float*)d_in[5];
    const float* att1 = (const float*)d_in[6];
    const float* b1   = (const float*)d_in[7];
    const float* Wl2  = (const float*)d_in[8];
    const float* Wr2  = (const float*)d_in[9];
    const float* att2 = (const float*)d_in[10];
    const float* b2   = (const float*)d_in[11];
    float* out = (float*)d_out;

    float* ws   = (float*)d_ws;
    float* x    = ws;                 // N*CIN
    float* xl1  = x   + N * CIN;      // N*F1
    float* xr1  = xl1 + N * F1;       // N*F1
    float* acc1 = xr1 + N * F1;       // N*F1
    float* s1   = acc1 + N * F1;      // N*H1
    float* dn1  = s1 + N * H1;        // N*H1
    float* s2   = dn1 + N * H1;       // N
    float* dn2  = s2 + N;             // N
    // reuse: x dead after g1+edge1 (g2 input is acc1); xl1/xr1 dead after edge1
    float* xl2  = x;                  // N*F2
    float* xr2  = xl1;                // N*F2
    float* acc2 = xl1 + N * F2;       // N*F2

    hipMemsetAsync(d_out, 0, (size_t)out_size * sizeof(float), stream);

    k_temb<<<N / 32, 256, 0, stream>>>(in, Wt, bt, x);
    g1<<<N / 32, 256, 0, stream>>>(x, Wl1, Wr1, att1, xl1, xr1, acc1, s1, dn1);
    k_edge1<<<E, 256, 0, stream>>>(ei, xl1, xr1, att1, s1, dn1, acc1);
    g2<<<N / 32, 256, 0, stream>>>(acc1, dn1, b1, Wl2, Wr2, att2, xl2, xr2, acc2, s2, dn2);
    k_edge2<<<E / 4, 256, 0, stream>>>(ei, xl2, xr2, att2, s2, dn2, acc2);
    k_out<<<dim3(BSZ, 64), 128, 0, stream>>>(acc2, dn2, b2, out);
}

// Round 4
// 210.246 us; speedup vs baseline: 1.3155x; 1.0803x over previous
//
#include <hip/hip_runtime.h>
#include <hip/hip_bf16.h>
#include <math.h>

#define NEG_SLOPE 0.2f

constexpr int BSZ = 8, T = 100, NN = 2048, N = BSZ * NN; // N = 16384
constexpr int CIN = 128, H1 = 4, F1 = 256, F2 = 128;
constexpr int E = 32768;

__device__ inline void fma4(float4& a, float s, const float4& w) {
    a.x = fmaf(s, w.x, a.x); a.y = fmaf(s, w.y, a.y);
    a.z = fmaf(s, w.z, a.z); a.w = fmaf(s, w.w, a.w);
}
__device__ inline float4 z4() { return make_float4(0.f, 0.f, 0.f, 0.f); }
__device__ inline float lrelu(float m) { return m > 0.f ? m : NEG_SLOPE * m; }
__device__ inline float eluf(float v) { return v > 0.f ? v : expm1f(v); }
__device__ inline float ldot(const float4& a, const float4& b, const float4& at) {
    return lrelu(a.x + b.x) * at.x + lrelu(a.y + b.y) * at.y +
           lrelu(a.z + b.z) * at.z + lrelu(a.w + b.w) * at.w;
}

// ---------- CSR build (dst in [0,NN)) ----------
__global__ __launch_bounds__(256) void k_hist(const int* __restrict__ ei,
        int* __restrict__ cnt) {
    int i = blockIdx.x * 256 + threadIdx.x;
    atomicAdd(&cnt[ei[E + i]], 1);
}

// single block: exclusive scan of 2048 counts -> off[2049], cur[2048]=off
__global__ __launch_bounds__(256) void k_scan(int* __restrict__ off,
        int* __restrict__ cnt_cur) {
    __shared__ int sc[256];
    int t = threadIdx.x;
    int base = t * 8;
    int local[8];
    int s = 0;
    #pragma unroll
    for (int j = 0; j < 8; ++j) { local[j] = s; s += cnt_cur[base + j]; }
    sc[t] = s;
    __syncthreads();
    for (int o = 1; o < 256; o <<= 1) {
        int v = (t >= o) ? sc[t - o] : 0;
        __syncthreads();
        sc[t] += v;
        __syncthreads();
    }
    int ex = sc[t] - s;
    #pragma unroll
    for (int j = 0; j < 8; ++j) {
        off[base + j] = ex + local[j];
        cnt_cur[base + j] = ex + local[j];
    }
    if (t == 255) off[2048] = sc[255];
}

__global__ __launch_bounds__(256) void k_scatter(const int* __restrict__ ei,
        int* __restrict__ cur, int* __restrict__ srcs) {
    int i = blockIdx.x * 256 + threadIdx.x;
    int d = ei[E + i];
    int pos = atomicAdd(&cur[d], 1);
    srcs[pos] = ei[i];
}

// ---------- K1: temporal embedding GEMM ----------
__global__ __launch_bounds__(256) void k_temb(const float* __restrict__ in,
        const float* __restrict__ Wt, const float* __restrict__ bt,
        float* __restrict__ x) {
    constexpr int STR = 36;
    alignas(16) __shared__ float xs[T * STR];
    alignas(16) __shared__ float ws[T * CIN];
    const int t = threadIdx.x;
    const int tc = t & 31, tr = t >> 5;
    const int row0 = blockIdx.x * 32;
    const int b = row0 / NN, node0 = row0 % NN;
    for (int i = t; i < T * 32; i += 256) {
        int tk = i >> 5, r = i & 31;
        xs[tk * STR + r] = in[(b * T + tk) * NN + node0 + r];
    }
    for (int i = t; i < T * CIN / 4; i += 256)
        ((float4*)ws)[i] = ((const float4*)Wt)[i];
    __syncthreads();
    float4 acc[4] = {z4(), z4(), z4(), z4()};
    #pragma unroll 4
    for (int k = 0; k < T; ++k) {
        float4 xv = *(const float4*)&xs[k * STR + tr * 4];
        float4 wv = *(const float4*)&ws[k * CIN + tc * 4];
        fma4(acc[0], xv.x, wv); fma4(acc[1], xv.y, wv);
        fma4(acc[2], xv.z, wv); fma4(acc[3], xv.w, wv);
    }
    float4 bv = *(const float4*)&bt[tc * 4];
    #pragma unroll
    for (int r = 0; r < 4; ++r) {
        float4 o = acc[r];
        o.x += bv.x; o.y += bv.y; o.z += bv.z; o.w += bv.w;
        *(float4*)&x[(row0 + tr * 4 + r) * CIN + tc * 4] = o;
    }
}

// ---------- G1: layer-1 dual GEMM + fused self-logit/init ----------
__global__ __launch_bounds__(256) void g1(const float* __restrict__ X,
        const float* __restrict__ Wl, const float* __restrict__ Wr,
        const float* __restrict__ att,
        float* __restrict__ xl, float* __restrict__ xr,
        float* __restrict__ acc1, float* __restrict__ s1, float* __restrict__ dn1) {
    constexpr int KT = 32, STR = 36;
    alignas(16) __shared__ float xs[KT * STR];
    alignas(16) __shared__ float wls[KT * F1];
    alignas(16) __shared__ float wrs[KT * F1];
    const int t = threadIdx.x;
    const int tc = t & 31, tr = t >> 5;
    const int row0 = blockIdx.x * 32;
    float4 aL0[4] = {z4(), z4(), z4(), z4()}, aL1[4] = {z4(), z4(), z4(), z4()};
    float4 aR0[4] = {z4(), z4(), z4(), z4()}, aR1[4] = {z4(), z4(), z4(), z4()};
    for (int kt = 0; kt < CIN; kt += KT) {
        __syncthreads();
        {
            int r = t >> 3, kq = t & 7;
            float4 v = *(const float4*)&X[(row0 + r) * CIN + kt + kq * 4];
            xs[(4 * kq + 0) * STR + r] = v.x;
            xs[(4 * kq + 1) * STR + r] = v.y;
            xs[(4 * kq + 2) * STR + r] = v.z;
            xs[(4 * kq + 3) * STR + r] = v.w;
        }
        #pragma unroll
        for (int it = 0; it < 8; ++it) {
            int idx = t + it * 256;
            int kk = idx >> 6, c4 = idx & 63;
            *(float4*)&wls[kk * F1 + c4 * 4] = *(const float4*)&Wl[(kt + kk) * F1 + c4 * 4];
            *(float4*)&wrs[kk * F1 + c4 * 4] = *(const float4*)&Wr[(kt + kk) * F1 + c4 * 4];
        }
        __syncthreads();
        #pragma unroll 4
        for (int kk = 0; kk < KT; ++kk) {
            float4 xv  = *(const float4*)&xs[kk * STR + tr * 4];
            float4 wl0 = *(const float4*)&wls[kk * F1 + tc * 4];
            float4 wl1 = *(const float4*)&wls[kk * F1 + 128 + tc * 4];
            float4 wr0 = *(const float4*)&wrs[kk * F1 + tc * 4];
            float4 wr1 = *(const float4*)&wrs[kk * F1 + 128 + tc * 4];
            fma4(aL0[0], xv.x, wl0); fma4(aL1[0], xv.x, wl1);
            fma4(aR0[0], xv.x, wr0); fma4(aR1[0], xv.x, wr1);
            fma4(aL0[1], xv.y, wl0); fma4(aL1[1], xv.y, wl1);
            fma4(aR0[1], xv.y, wr0); fma4(aR1[1], xv.y, wr1);
            fma4(aL0[2], xv.z, wl0); fma4(aL1[2], xv.z, wl1);
            fma4(aR0[2], xv.z, wr0); fma4(aR1[2], xv.z, wr1);
            fma4(aL0[3], xv.w, wl0); fma4(aL1[3], xv.w, wl1);
            fma4(aR0[3], xv.w, wr0); fma4(aR1[3], xv.w, wr1);
        }
    }
    float4 at0 = *(const float4*)&att[tc * 4];
    float4 at1 = *(const float4*)&att[128 + tc * 4];
    #pragma unroll
    for (int r = 0; r < 4; ++r) {
        int row = row0 + tr * 4 + r;
        *(float4*)&xl[row * F1 + tc * 4]         = aL0[r];
        *(float4*)&xl[row * F1 + 128 + tc * 4]   = aL1[r];
        *(float4*)&xr[row * F1 + tc * 4]         = aR0[r];
        *(float4*)&xr[row * F1 + 128 + tc * 4]   = aR1[r];
        *(float4*)&acc1[row * F1 + tc * 4]       = aL0[r];
        *(float4*)&acc1[row * F1 + 128 + tc * 4] = aL1[r];
        float p0 = ldot(aL0[r], aR0[r], at0);
        float p1 = ldot(aL1[r], aR1[r], at1);
        #pragma unroll
        for (int off = 8; off; off >>= 1) {
            p0 += __shfl_xor(p0, off, 64);
            p1 += __shfl_xor(p1, off, 64);
        }
        if ((tc & 15) == 0) {
            int h = tc >> 4;
            s1[row * H1 + h]      = p0;
            s1[row * H1 + 2 + h]  = p1;
            dn1[row * H1 + h]     = 1.0f;
            dn1[row * H1 + 2 + h] = 1.0f;
        }
    }
}

// ---------- gather edge pass, layer 1: one block per dst node ----------
__global__ __launch_bounds__(256) void k_gat1(const int* __restrict__ off,
        const int* __restrict__ srcs, const float* __restrict__ xl,
        const float* __restrict__ xr, const float* __restrict__ att,
        const float* __restrict__ s1, float* __restrict__ acc1,
        float* __restrict__ dn1) {
    const int d = blockIdx.x;
    const int t = threadIdx.x;
    const int wv = t >> 6, c = t & 63;
    const int e0 = off[d], e1 = off[d + 1];
    float b[4], at[4], sh[4], acc[4] = {0,0,0,0}, dnl[4] = {0,0,0,0};
    #pragma unroll
    for (int k = 0; k < 4; ++k) {
        b[k]  = xr[d * F1 + c + 64 * k];
        at[k] = att[c + 64 * k];
        sh[k] = s1[d * H1 + k];
    }
    for (int e = e0 + wv; e < e1; e += 4) {
        int s = srcs[e];
        float a[4], p[4];
        #pragma unroll
        for (int k = 0; k < 4; ++k) {
            a[k] = xl[s * F1 + c + 64 * k];
            p[k] = lrelu(a[k] + b[k]) * at[k];
        }
        #pragma unroll
        for (int o = 32; o; o >>= 1) {
            #pragma unroll
            for (int k = 0; k < 4; ++k) p[k] += __shfl_xor(p[k], o, 64);
        }
        #pragma unroll
        for (int k = 0; k < 4; ++k) {
            float w = 8.0f * __expf(p[k] - sh[k]);
            dnl[k] += w;
            acc[k] = fmaf(w, a[k], acc[k]);
        }
    }
    __shared__ float lacc[4][F1];
    __shared__ float ldn[4][4];
    #pragma unroll
    for (int k = 0; k < 4; ++k) lacc[wv][c + 64 * k] = acc[k];
    if (c < 4) ldn[wv][c] = dnl[c];  // note: dnl identical across lanes post-reduce
    __syncthreads();
    int f = t;
    float tot = xl[d * F1 + f] + lacc[0][f] + lacc[1][f] + lacc[2][f] + lacc[3][f];
    acc1[d * F1 + f] = tot;
    if (t < 4) dn1[d * H1 + t] = 1.0f + ldn[0][t] + ldn[1][t] + ldn[2][t] + ldn[3][t];
}

// ---------- G2: layer-2 dual GEMM, fin1 fused in staging, self-logit epilogue ----------
__global__ __launch_bounds__(256) void g2(const float* __restrict__ A1,
        const float* __restrict__ dn1, const float* __restrict__ b1,
        const float* __restrict__ Wl, const float* __restrict__ Wr,
        const float* __restrict__ att,
        float* __restrict__ xl2, float* __restrict__ xr2,
        float* __restrict__ acc2, float* __restrict__ s2, float* __restrict__ dn2) {
    constexpr int KT = 32, STR = 36;
    alignas(16) __shared__ float xs[KT * STR];
    alignas(16) __shared__ float wls[KT * F2];
    alignas(16) __shared__ float wrs[KT * F2];
    const int t = threadIdx.x;
    const int tc = t & 31, tr = t >> 5;
    const int row0 = blockIdx.x * 32;
    float4 aL[4] = {z4(), z4(), z4(), z4()}, aR[4] = {z4(), z4(), z4(), z4()};
    for (int kt = 0; kt < F1; kt += KT) {
        __syncthreads();
        {
            int r = t >> 3, kq = t & 7;
            int node = row0 + r, col = kt + kq * 4;
            float4 v = *(const float4*)&A1[node * F1 + col];
            float rd = 1.0f / (dn1[node * H1 + (col >> 6)] + 1e-16f);
            float4 bv = *(const float4*)&b1[col];
            v.x = eluf(v.x * rd + bv.x); v.y = eluf(v.y * rd + bv.y);
            v.z = eluf(v.z * rd + bv.z); v.w = eluf(v.w * rd + bv.w);
            xs[(4 * kq + 0) * STR + r] = v.x;
            xs[(4 * kq + 1) * STR + r] = v.y;
            xs[(4 * kq + 2) * STR + r] = v.z;
            xs[(4 * kq + 3) * STR + r] = v.w;
        }
        #pragma unroll
        for (int it = 0; it < 4; ++it) {
            int idx = t + it * 256;
            int kk = idx >> 5, c4 = idx & 31;
            *(float4*)&wls[kk * F2 + c4 * 4] = *(const float4*)&Wl[(kt + kk) * F2 + c4 * 4];
            *(float4*)&wrs[kk * F2 + c4 * 4] = *(const float4*)&Wr[(kt + kk) * F2 + c4 * 4];
        }
        __syncthreads();
        #pragma unroll 4
        for (int kk = 0; kk < KT; ++kk) {
            float4 xv = *(const float4*)&xs[kk * STR + tr * 4];
            float4 wl = *(const float4*)&wls[kk * F2 + tc * 4];
            float4 wr = *(const float4*)&wrs[kk * F2 + tc * 4];
            fma4(aL[0], xv.x, wl); fma4(aR[0], xv.x, wr);
            fma4(aL[1], xv.y, wl); fma4(aR[1], xv.y, wr);
            fma4(aL[2], xv.z, wl); fma4(aR[2], xv.z, wr);
            fma4(aL[3], xv.w, wl); fma4(aR[3], xv.w, wr);
        }
    }
    float4 av = *(const float4*)&att[tc * 4];
    #pragma unroll
    for (int r = 0; r < 4; ++r) {
        int row = row0 + tr * 4 + r;
        *(float4*)&xl2[row * F2 + tc * 4]  = aL[r];
        *(float4*)&xr2[row * F2 + tc * 4]  = aR[r];
        *(float4*)&acc2[row * F2 + tc * 4] = aL[r];
        float p = ldot(aL[r], aR[r], av);
        #pragma unroll
        for (int off = 16; off; off >>= 1) p += __shfl_xor(p, off, 64);
        if (tc == 0) { s2[row] = p; dn2[row] = 1.0f; }
    }
}

// ---------- gather edge pass, layer 2 ----------
__global__ __launch_bounds__(256) void k_gat2(const int* __restrict__ off,
        const int* __restrict__ srcs, const float* __restrict__ xl,
        const float* __restrict__ xr, const float* __restrict__ att,
        const float* __restrict__ s2, float* __restrict__ acc2,
        float* __restrict__ dn2) {
    const int d = blockIdx.x;
    const int t = threadIdx.x;
    const int wv = t >> 6, c = t & 63;
    const int e0 = off[d], e1 = off[d + 1];
    float b0 = xr[d * F2 + c], b1v = xr[d * F2 + c + 64];
    float at0 = att[c], at1 = att[c + 64];
    float sh = s2[d];
    float acc0 = 0.f, acc1v = 0.f, dnl = 0.f;
    for (int e = e0 + wv; e < e1; e += 4) {
        int s = srcs[e];
        float a0 = xl[s * F2 + c], a1 = xl[s * F2 + c + 64];
        float p = lrelu(a0 + b0) * at0 + lrelu(a1 + b1v) * at1;
        #pragma unroll
        for (int o = 32; o; o >>= 1) p += __shfl_xor(p, o, 64);
        float w = 8.0f * __expf(p - sh);
        dnl += w;
        acc0 = fmaf(w, a0, acc0);
        acc1v = fmaf(w, a1, acc1v);
    }
    __shared__ float lacc[4][F2];
    __shared__ float ldn[4];
    lacc[wv][c] = acc0;
    lacc[wv][c + 64] = acc1v;
    if (c == 0) ldn[wv] = dnl;
    __syncthreads();
    if (t < F2) {
        int f = t;
        float tot = xl[d * F2 + f] + lacc[0][f] + lacc[1][f] + lacc[2][f] + lacc[3][f];
        acc2[d * F2 + f] = tot;
    }
    if (t == 0) dn2[d] = 1.0f + ldn[0] + ldn[1] + ldn[2] + ldn[3];
}

// ---------- K9: batched mean ----------
__global__ __launch_bounds__(128) void k_out(const float* __restrict__ accum,
        const float* __restrict__ dn, const float* __restrict__ b2,
        float* __restrict__ out) {
    int b = blockIdx.x, chunk = blockIdx.y;
    int c = threadIdx.x;
    float acc = 0.f;
    int n0 = b * NN + chunk * 32;
    for (int i = 0; i < 32; ++i) {
        int node = n0 + i;
        acc += accum[node * F2 + c] / (dn[node] + 1e-16f);
    }
    float val = acc * (1.0f / NN);
    if (chunk == 0) val += b2[c];
    atomicAdd(&out[b * F2 + c], val);
}

extern "C" void kernel_launch(void* const* d_in, const int* in_sizes, int n_in,
                              void* d_out, int out_size, void* d_ws, size_t ws_size,
                              hipStream_t stream) {
    const float* in   = (const float*)d_in[0];
    const int*   ei   = (const int*)d_in[1];
    const float* Wt   = (const float*)d_in[2];
    const float* bt   = (const float*)d_in[3];
    const float* Wl1  = (const float*)d_in[4];
    const float* Wr1  = (const float*)d_in[5];
    const float* att1 = (const float*)d_in[6];
    const float* b1   = (const float*)d_in[7];
    const float* Wl2  = (const float*)d_in[8];
    const float* Wr2  = (const float*)d_in[9];
    const float* att2 = (const float*)d_in[10];
    const float* b2   = (const float*)d_in[11];
    float* out = (float*)d_out;

    float* ws   = (float*)d_ws;
    float* x    = ws;                 // N*CIN
    float* xl1  = x   + N * CIN;      // N*F1
    float* xr1  = xl1 + N * F1;       // N*F1
    float* acc1 = xr1 + N * F1;       // N*F1
    float* s1   = acc1 + N * F1;      // N*H1
    float* dn1  = s1 + N * H1;        // N*H1
    float* s2   = dn1 + N * H1;       // N
    float* dn2  = s2 + N;             // N
    int* off    = (int*)(dn2 + N);    // NN+1
    int* cur    = off + (NN + 1);     // NN
    int* srcs   = cur + NN;           // E
    // reuse: x dead after g1 (g2 input is acc1); xl1/xr1 dead after k_gat1
    float* xl2  = x;                  // N*F2
    float* xr2  = xl1;                // N*F2
    float* acc2 = xl1 + N * F2;       // N*F2

    hipMemsetAsync(d_out, 0, (size_t)out_size * sizeof(float), stream);
    hipMemsetAsync(cur, 0, NN * sizeof(int), stream);

    k_hist<<<E / 256, 256, 0, stream>>>(ei, cur);
    k_scan<<<1, 256, 0, stream>>>(off, cur);
    k_scatter<<<E / 256, 256, 0, stream>>>(ei, cur, srcs);
    k_temb<<<N / 32, 256, 0, stream>>>(in, Wt, bt, x);
    g1<<<N / 32, 256, 0, stream>>>(x, Wl1, Wr1, att1, xl1, xr1, acc1, s1, dn1);
    k_gat1<<<NN, 256, 0, stream>>>(off, srcs, xl1, xr1, att1, s1, acc1, dn1);
    g2<<<N / 32, 256, 0, stream>>>(acc1, dn1, b1, Wl2, Wr2, att2, xl2, xr2, acc2, s2, dn2);
    k_gat2<<<NN, 256, 0, stream>>>(off, srcs, xl2, xr2, att2, s2, acc2, dn2);
    k_out<<<dim3(BSZ, 64), 128, 0, stream>>>(acc2, dn2, b2, out);
}

// Round 5
// 191.995 us; speedup vs baseline: 1.4406x; 1.0951x over previous
//
#include <hip/hip_runtime.h>
#include <hip/hip_bf16.h>
#include <math.h>

#define NEG_SLOPE 0.2f

constexpr int BSZ = 8, T = 100, NN = 2048, N = BSZ * NN; // N = 16384
constexpr int CIN = 128, H1 = 4, F1 = 256, F2 = 128;
constexpr int E = 32768;

typedef _Float16 f16x8 __attribute__((ext_vector_type(8)));
typedef _Float16 f16x4 __attribute__((ext_vector_type(4)));
typedef float f32x4 __attribute__((ext_vector_type(4)));

__device__ inline void fma4(float4& a, float s, const float4& w) {
    a.x = fmaf(s, w.x, a.x); a.y = fmaf(s, w.y, a.y);
    a.z = fmaf(s, w.z, a.z); a.w = fmaf(s, w.w, a.w);
}
__device__ inline float4 z4() { return make_float4(0.f, 0.f, 0.f, 0.f); }
__device__ inline float lrelu(float m) { return m > 0.f ? m : NEG_SLOPE * m; }
__device__ inline float eluf(float v) { return v > 0.f ? v : expm1f(v); }

// ---------- weight transpose + fp32->f16 convert: WT[n][k] = (f16)W[k][n] ----------
__global__ __launch_bounds__(256) void k_wt(const float* __restrict__ Wl1,
        const float* __restrict__ Wr1, const float* __restrict__ Wl2,
        const float* __restrict__ Wr2, _Float16* __restrict__ Tl1,
        _Float16* __restrict__ Tr1, _Float16* __restrict__ Tl2,
        _Float16* __restrict__ Tr2) {
    int which = blockIdx.y;
    const float* src = which == 0 ? Wl1 : which == 1 ? Wr1 : which == 2 ? Wl2 : Wr2;
    _Float16* dst    = which == 0 ? Tl1 : which == 1 ? Tr1 : which == 2 ? Tl2 : Tr2;
    int K  = which < 2 ? CIN : F1;
    int Nc = which < 2 ? F1 : F2;
    int tilesN = Nc / 32;
    int tk = (blockIdx.x / tilesN) * 32, tn = (blockIdx.x % tilesN) * 32;
    __shared__ _Float16 tile[32][33];
    int tx = threadIdx.x & 31, ty = threadIdx.x >> 5;
    for (int r = ty; r < 32; r += 8)
        tile[r][tx] = (_Float16)src[(tk + r) * Nc + tn + tx];
    __syncthreads();
    for (int r = ty; r < 32; r += 8)
        dst[(tn + r) * K + tk + tx] = tile[tx][r];
}

// ---------- CSR build (dst in [0,NN)) ----------
__global__ __launch_bounds__(256) void k_hist(const int* __restrict__ ei,
        int* __restrict__ cnt) {
    int i = blockIdx.x * 256 + threadIdx.x;
    atomicAdd(&cnt[ei[E + i]], 1);
}

__global__ __launch_bounds__(256) void k_scan(int* __restrict__ off,
        int* __restrict__ cnt_cur) {
    __shared__ int sc[256];
    int t = threadIdx.x;
    int base = t * 8;
    int local[8];
    int s = 0;
    #pragma unroll
    for (int j = 0; j < 8; ++j) { local[j] = s; s += cnt_cur[base + j]; }
    sc[t] = s;
    __syncthreads();
    for (int o = 1; o < 256; o <<= 1) {
        int v = (t >= o) ? sc[t - o] : 0;
        __syncthreads();
        sc[t] += v;
        __syncthreads();
    }
    int ex = sc[t] - s;
    #pragma unroll
    for (int j = 0; j < 8; ++j) {
        off[base + j] = ex + local[j];
        cnt_cur[base + j] = ex + local[j];
    }
    if (t == 255) off[2048] = sc[255];
}

__global__ __launch_bounds__(256) void k_scatter(const int* __restrict__ ei,
        int* __restrict__ cur, int* __restrict__ srcs) {
    int i = blockIdx.x * 256 + threadIdx.x;
    int d = ei[E + i];
    int pos = atomicAdd(&cur[d], 1);
    srcs[pos] = ei[i];
}

// ---------- K1: temporal embedding GEMM (fp32 VALU), writes f16 ----------
__global__ __launch_bounds__(256) void k_temb(const float* __restrict__ in,
        const float* __restrict__ Wt, const float* __restrict__ bt,
        _Float16* __restrict__ xh) {
    constexpr int STR = 36;
    alignas(16) __shared__ float xs[T * STR];
    alignas(16) __shared__ float wsh[T * CIN];
    const int t = threadIdx.x;
    const int tc = t & 31, tr = t >> 5;
    const int row0 = blockIdx.x * 32;
    const int b = row0 / NN, node0 = row0 % NN;
    for (int i = t; i < T * 32; i += 256) {
        int tk = i >> 5, r = i & 31;
        xs[tk * STR + r] = in[(b * T + tk) * NN + node0 + r];
    }
    for (int i = t; i < T * CIN / 4; i += 256)
        ((float4*)wsh)[i] = ((const float4*)Wt)[i];
    __syncthreads();
    float4 acc[4] = {z4(), z4(), z4(), z4()};
    #pragma unroll 4
    for (int k = 0; k < T; ++k) {
        float4 xv = *(const float4*)&xs[k * STR + tr * 4];
        float4 wv = *(const float4*)&wsh[k * CIN + tc * 4];
        fma4(acc[0], xv.x, wv); fma4(acc[1], xv.y, wv);
        fma4(acc[2], xv.z, wv); fma4(acc[3], xv.w, wv);
    }
    float4 bv = *(const float4*)&bt[tc * 4];
    #pragma unroll
    for (int r = 0; r < 4; ++r) {
        float4 o = acc[r];
        f16x4 ov = { (_Float16)(o.x + bv.x), (_Float16)(o.y + bv.y),
                     (_Float16)(o.z + bv.z), (_Float16)(o.w + bv.w) };
        *(f16x4*)&xh[(row0 + tr * 4 + r) * CIN + tc * 4] = ov;
    }
}

// ---------- GM1: layer-1 dual GEMM via MFMA f16 + fused self-logit ----------
// 32 rows/block; wave: strip=wave&1 (16 rows), half=wave>>1 (128 cols)
__global__ __launch_bounds__(256) void gm1(const _Float16* __restrict__ Xh,
        const _Float16* __restrict__ BTl, const _Float16* __restrict__ BTr,
        const float* __restrict__ att,
        float* __restrict__ xl, float* __restrict__ xr,
        float* __restrict__ acc1, float* __restrict__ s1, float* __restrict__ dn1) {
    const int t = threadIdx.x;
    const int wave = t >> 6, lane = t & 63;
    const int quad = lane >> 4, l15 = lane & 15;
    const int strip = wave & 1, half = wave >> 1;
    const int row0 = blockIdx.x * 32;
    const int arow = row0 + strip * 16 + l15;
    const int kq = quad * 8;
    f32x4 aL[8], aR[8];
    #pragma unroll
    for (int i = 0; i < 8; ++i) { aL[i] = (f32x4){0,0,0,0}; aR[i] = (f32x4){0,0,0,0}; }
    #pragma unroll 2
    for (int kt = 0; kt < CIN; kt += 32) {
        f16x8 af = *(const f16x8*)&Xh[arow * CIN + kt + kq];
        #pragma unroll
        for (int ct = 0; ct < 8; ++ct) {
            int n = half * 128 + ct * 16 + l15;
            f16x8 bl = *(const f16x8*)&BTl[n * CIN + kt + kq];
            f16x8 br = *(const f16x8*)&BTr[n * CIN + kt + kq];
            aL[ct] = __builtin_amdgcn_mfma_f32_16x16x32_f16(af, bl, aL[ct], 0, 0, 0);
            aR[ct] = __builtin_amdgcn_mfma_f32_16x16x32_f16(af, br, aR[ct], 0, 0, 0);
        }
    }
    const int rbase = row0 + strip * 16 + quad * 4;
    const int cbase = half * 128;
    if (row0 < NN) {
        float pH0[4] = {0,0,0,0}, pH1[4] = {0,0,0,0};
        #pragma unroll
        for (int ct = 0; ct < 8; ++ct) {
            int col = cbase + ct * 16 + l15;
            float av = att[col];
            #pragma unroll
            for (int r = 0; r < 4; ++r) {
                float L = aL[ct][r], R = aR[ct][r];
                xl[(rbase + r) * F1 + col] = L;
                xr[(rbase + r) * F1 + col] = R;
                float q = lrelu(L + R) * av;
                if (ct < 4) pH0[r] += q; else pH1[r] += q;
            }
        }
        #pragma unroll
        for (int r = 0; r < 4; ++r) {
            float p0 = pH0[r], p1 = pH1[r];
            p0 += __shfl_xor(p0, 1, 64); p1 += __shfl_xor(p1, 1, 64);
            p0 += __shfl_xor(p0, 2, 64); p1 += __shfl_xor(p1, 2, 64);
            p0 += __shfl_xor(p0, 4, 64); p1 += __shfl_xor(p1, 4, 64);
            p0 += __shfl_xor(p0, 8, 64); p1 += __shfl_xor(p1, 8, 64);
            if (l15 == 0) {
                s1[(rbase + r) * H1 + half * 2 + 0] = p0;
                s1[(rbase + r) * H1 + half * 2 + 1] = p1;
            }
        }
    } else {
        #pragma unroll
        for (int ct = 0; ct < 8; ++ct) {
            int col = cbase + ct * 16 + l15;
            #pragma unroll
            for (int r = 0; r < 4; ++r)
                acc1[(rbase + r) * F1 + col] = aL[ct][r];
        }
        if (t < 128) dn1[row0 * H1 + t] = 1.0f;
    }
}

// ---------- gather edge pass, layer 1 ----------
__global__ __launch_bounds__(256) void k_gat1(const int* __restrict__ off,
        const int* __restrict__ srcs, const float* __restrict__ xl,
        const float* __restrict__ xr, const float* __restrict__ att,
        const float* __restrict__ s1, float* __restrict__ acc1,
        float* __restrict__ dn1) {
    const int d = blockIdx.x;
    const int t = threadIdx.x;
    const int wv = t >> 6, c = t & 63;
    const int e0 = off[d], e1 = off[d + 1];
    float b[4], at[4], sh[4], acc[4] = {0,0,0,0}, dnl[4] = {0,0,0,0};
    #pragma unroll
    for (int k = 0; k < 4; ++k) {
        b[k]  = xr[d * F1 + c + 64 * k];
        at[k] = att[c + 64 * k];
        sh[k] = s1[d * H1 + k];
    }
    for (int e = e0 + wv; e < e1; e += 4) {
        int s = srcs[e];
        float a[4], p[4];
        #pragma unroll
        for (int k = 0; k < 4; ++k) {
            a[k] = xl[s * F1 + c + 64 * k];
            p[k] = lrelu(a[k] + b[k]) * at[k];
        }
        #pragma unroll
        for (int o = 32; o; o >>= 1) {
            #pragma unroll
            for (int k = 0; k < 4; ++k) p[k] += __shfl_xor(p[k], o, 64);
        }
        #pragma unroll
        for (int k = 0; k < 4; ++k) {
            float w = 8.0f * __expf(p[k] - sh[k]);
            dnl[k] += w;
            acc[k] = fmaf(w, a[k], acc[k]);
        }
    }
    __shared__ float lacc[4][F1];
    __shared__ float ldn[4][4];
    #pragma unroll
    for (int k = 0; k < 4; ++k) lacc[wv][c + 64 * k] = acc[k];
    if (c < 4) ldn[wv][c] = dnl[c];
    __syncthreads();
    int f = t;
    float tot = xl[d * F1 + f] + lacc[0][f] + lacc[1][f] + lacc[2][f] + lacc[3][f];
    acc1[d * F1 + f] = tot;
    if (t < 4) dn1[d * H1 + t] = 1.0f + ldn[0][t] + ldn[1][t] + ldn[2][t] + ldn[3][t];
}

// ---------- fin1: h1_h = (f16) elu(acc1/dn1 + b1) ----------
__global__ __launch_bounds__(256) void k_fin(const float* __restrict__ acc1,
        const float* __restrict__ dn1, const float* __restrict__ b1,
        _Float16* __restrict__ h1h) {
    int idx = blockIdx.x * 256 + threadIdx.x;  // one float4 each
    int node = idx >> 6, cq = idx & 63;
    float4 v = *(const float4*)&acc1[idx * 4];
    float rd = 1.0f / (dn1[node * H1 + (cq >> 4)] + 1e-16f);
    float4 bv = *(const float4*)&b1[cq * 4];
    f16x4 o = { (_Float16)eluf(v.x * rd + bv.x), (_Float16)eluf(v.y * rd + bv.y),
                (_Float16)eluf(v.z * rd + bv.z), (_Float16)eluf(v.w * rd + bv.w) };
    *(f16x4*)&h1h[idx * 4] = o;
}

// ---------- GM2: layer-2 dual GEMM via MFMA f16 + fused self-logit ----------
__global__ __launch_bounds__(256) void gm2(const _Float16* __restrict__ Xh,
        const _Float16* __restrict__ BTl, const _Float16* __restrict__ BTr,
        const float* __restrict__ att,
        float* __restrict__ xl2, float* __restrict__ xr2,
        float* __restrict__ acc2, float* __restrict__ s2, float* __restrict__ dn2) {
    const int t = threadIdx.x;
    const int wave = t >> 6, lane = t & 63;
    const int quad = lane >> 4, l15 = lane & 15;
    const int strip = wave & 1, half = wave >> 1;
    const int row0 = blockIdx.x * 32;
    const int arow = row0 + strip * 16 + l15;
    const int kq = quad * 8;
    f32x4 aL[4], aR[4];
    #pragma unroll
    for (int i = 0; i < 4; ++i) { aL[i] = (f32x4){0,0,0,0}; aR[i] = (f32x4){0,0,0,0}; }
    #pragma unroll 2
    for (int kt = 0; kt < F1; kt += 32) {
        f16x8 af = *(const f16x8*)&Xh[arow * F1 + kt + kq];
        #pragma unroll
        for (int ct = 0; ct < 4; ++ct) {
            int n = half * 64 + ct * 16 + l15;
            f16x8 bl = *(const f16x8*)&BTl[n * F1 + kt + kq];
            f16x8 br = *(const f16x8*)&BTr[n * F1 + kt + kq];
            aL[ct] = __builtin_amdgcn_mfma_f32_16x16x32_f16(af, bl, aL[ct], 0, 0, 0);
            aR[ct] = __builtin_amdgcn_mfma_f32_16x16x32_f16(af, br, aR[ct], 0, 0, 0);
        }
    }
    const int rbase = row0 + strip * 16 + quad * 4;
    const int cbase = half * 64;
    if (row0 < NN) {
        __shared__ float part[2][16][2];
        float pr[4] = {0,0,0,0};
        #pragma unroll
        for (int ct = 0; ct < 4; ++ct) {
            int col = cbase + ct * 16 + l15;
            float av = att[col];
            #pragma unroll
            for (int r = 0; r < 4; ++r) {
                float L = aL[ct][r], R = aR[ct][r];
                xl2[(rbase + r) * F2 + col] = L;
                xr2[(rbase + r) * F2 + col] = R;
                pr[r] += lrelu(L + R) * av;
            }
        }
        #pragma unroll
        for (int r = 0; r < 4; ++r) {
            float p = pr[r];
            p += __shfl_xor(p, 1, 64); p += __shfl_xor(p, 2, 64);
            p += __shfl_xor(p, 4, 64); p += __shfl_xor(p, 8, 64);
            if (l15 == 0) part[strip][quad * 4 + r][half] = p;
        }
        __syncthreads();
        if (t < 32) {
            int st = t >> 4, i = t & 15;
            s2[row0 + st * 16 + i] = part[st][i][0] + part[st][i][1];
        }
    } else {
        #pragma unroll
        for (int ct = 0; ct < 4; ++ct) {
            int col = cbase + ct * 16 + l15;
            #pragma unroll
            for (int r = 0; r < 4; ++r)
                acc2[(rbase + r) * F2 + col] = aL[ct][r];
        }
        if (t < 32) dn2[row0 + t] = 1.0f;
    }
}

// ---------- gather edge pass, layer 2 ----------
__global__ __launch_bounds__(256) void k_gat2(const int* __restrict__ off,
        const int* __restrict__ srcs, const float* __restrict__ xl,
        const float* __restrict__ xr, const float* __restrict__ att,
        const float* __restrict__ s2, float* __restrict__ acc2,
        float* __restrict__ dn2) {
    const int d = blockIdx.x;
    const int t = threadIdx.x;
    const int wv = t >> 6, c = t & 63;
    const int e0 = off[d], e1 = off[d + 1];
    float b0 = xr[d * F2 + c], b1v = xr[d * F2 + c + 64];
    float at0 = att[c], at1 = att[c + 64];
    float sh = s2[d];
    float acc0 = 0.f, acc1v = 0.f, dnl = 0.f;
    for (int e = e0 + wv; e < e1; e += 4) {
        int s = srcs[e];
        float a0 = xl[s * F2 + c], a1 = xl[s * F2 + c + 64];
        float p = lrelu(a0 + b0) * at0 + lrelu(a1 + b1v) * at1;
        #pragma unroll
        for (int o = 32; o; o >>= 1) p += __shfl_xor(p, o, 64);
        float w = 8.0f * __expf(p - sh);
        dnl += w;
        acc0 = fmaf(w, a0, acc0);
        acc1v = fmaf(w, a1, acc1v);
    }
    __shared__ float lacc[4][F2];
    __shared__ float ldn[4];
    lacc[wv][c] = acc0;
    lacc[wv][c + 64] = acc1v;
    if (c == 0) ldn[wv] = dnl;
    __syncthreads();
    if (t < F2) {
        int f = t;
        float tot = xl[d * F2 + f] + lacc[0][f] + lacc[1][f] + lacc[2][f] + lacc[3][f];
        acc2[d * F2 + f] = tot;
    }
    if (t == 0) dn2[d] = 1.0f + ldn[0] + ldn[1] + ldn[2] + ldn[3];
}

// ---------- K9: batched mean ----------
__global__ __launch_bounds__(128) void k_out(const float* __restrict__ accum,
        const float* __restrict__ dn, const float* __restrict__ b2,
        float* __restrict__ out) {
    int b = blockIdx.x, chunk = blockIdx.y;
    int c = threadIdx.x;
    float acc = 0.f;
    int n0 = b * NN + chunk * 32;
    for (int i = 0; i < 32; ++i) {
        int node = n0 + i;
        acc += accum[node * F2 + c] / (dn[node] + 1e-16f);
    }
    float val = acc * (1.0f / NN);
    if (chunk == 0) val += b2[c];
    atomicAdd(&out[b * F2 + c], val);
}

extern "C" void kernel_launch(void* const* d_in, const int* in_sizes, int n_in,
                              void* d_out, int out_size, void* d_ws, size_t ws_size,
                              hipStream_t stream) {
    const float* in   = (const float*)d_in[0];
    const int*   ei   = (const int*)d_in[1];
    const float* Wt   = (const float*)d_in[2];
    const float* bt   = (const float*)d_in[3];
    const float* Wl1  = (const float*)d_in[4];
    const float* Wr1  = (const float*)d_in[5];
    const float* att1 = (const float*)d_in[6];
    const float* b1   = (const float*)d_in[7];
    const float* Wl2  = (const float*)d_in[8];
    const float* Wr2  = (const float*)d_in[9];
    const float* att2 = (const float*)d_in[10];
    const float* b2   = (const float*)d_in[11];
    float* out = (float*)d_out;

    // workspace layout (floats unless noted)
    float* ws = (float*)d_ws;
    _Float16* xh = (_Float16*)ws;           // N*CIN f16   (4 MB)
    float* xl1   = ws + N * CIN / 2;        // N*F1        (16 MB)
    float* xr1   = xl1 + N * F1;            // N*F1
    float* acc1  = xr1 + N * F1;            // N*F1
    float* s1    = acc1 + N * F1;           // N*H1
    float* dn1   = s1 + N * H1;             // N*H1
    float* s2    = dn1 + N * H1;            // N
    float* dn2   = s2 + N;                  // N
    _Float16* T1l = (_Float16*)(dn2 + N);   // CIN*F1 f16
    _Float16* T1r = T1l + CIN * F1;
    _Float16* T2l = T1r + CIN * F1;         // F1*F2 f16
    _Float16* T2r = T2l + F1 * F2;
    int* off  = (int*)(T2r + F1 * F2);      // NN+1
    int* cur  = off + (NN + 1);             // NN
    int* srcs = cur + NN;                   // E
    // overlays (sequential stream, live ranges disjoint):
    _Float16* h1h = (_Float16*)xl1;         // N*F1 f16 in dead xl1
    float* xl2    = xr1;                    // N*F2 in dead xr1
    float* xr2    = xr1 + N * F2;
    float* acc2   = acc1;                   // N*F2 in dead acc1

    hipMemsetAsync(d_out, 0, (size_t)out_size * sizeof(float), stream);
    hipMemsetAsync(cur, 0, NN * sizeof(int), stream);

    k_wt<<<dim3(32, 4), 256, 0, stream>>>(Wl1, Wr1, Wl2, Wr2, T1l, T1r, T2l, T2r);
    k_hist<<<E / 256, 256, 0, stream>>>(ei, cur);
    k_scan<<<1, 256, 0, stream>>>(off, cur);
    k_scatter<<<E / 256, 256, 0, stream>>>(ei, cur, srcs);
    k_temb<<<N / 32, 256, 0, stream>>>(in, Wt, bt, xh);
    gm1<<<N / 32, 256, 0, stream>>>(xh, T1l, T1r, att1, xl1, xr1, acc1, s1, dn1);
    k_gat1<<<NN, 256, 0, stream>>>(off, srcs, xl1, xr1, att1, s1, acc1, dn1);
    k_fin<<<N * F1 / 1024, 256, 0, stream>>>(acc1, dn1, b1, h1h);
    gm2<<<N / 32, 256, 0, stream>>>(h1h, T2l, T2r, att2, xl2, xr2, acc2, s2, dn2);
    k_gat2<<<NN, 256, 0, stream>>>(off, srcs, xl2, xr2, att2, s2, acc2, dn2);
    k_out<<<dim3(BSZ, 64), 128, 0, stream>>>(acc2, dn2, b2, out);
}

// Round 9
// 171.757 us; speedup vs baseline: 1.6103x; 1.1178x over previous
//
#include <hip/hip_runtime.h>
#include <hip/hip_bf16.h>
#include <math.h>

#define NEG_SLOPE 0.2f

constexpr int BSZ = 8, T = 100, NN = 2048, N = BSZ * NN; // N = 16384
constexpr int CIN = 128, H1 = 4, F1 = 256, F2 = 128;
constexpr int E = 32768;
constexpr int KP = 40;  // padded LDS inner dim (f16) to break bank conflicts

typedef _Float16 f16x8 __attribute__((ext_vector_type(8)));
typedef _Float16 f16x4 __attribute__((ext_vector_type(4)));
typedef float f32x4 __attribute__((ext_vector_type(4)));

__device__ inline void fma4(float4& a, float s, const float4& w) {
    a.x = fmaf(s, w.x, a.x); a.y = fmaf(s, w.y, a.y);
    a.z = fmaf(s, w.z, a.z); a.w = fmaf(s, w.w, a.w);
}
__device__ inline float4 z4() { return make_float4(0.f, 0.f, 0.f, 0.f); }
__device__ inline float lrelu(float m) { return m > 0.f ? m : NEG_SLOPE * m; }
__device__ inline float eluf(float v) { return v > 0.f ? v : expm1f(v); }

// ---------- weight transpose + f16 convert: WT[n][k] = (f16)W[k][n] ----------
__global__ __launch_bounds__(256) void k_wt(const float* __restrict__ Wl1,
        const float* __restrict__ Wr1, const float* __restrict__ Wl2,
        const float* __restrict__ Wr2, _Float16* __restrict__ T1l,
        _Float16* __restrict__ T1r, _Float16* __restrict__ T2l,
        _Float16* __restrict__ T2r) {
    const int which = blockIdx.y;
    const float* src = which == 0 ? Wl1 : which == 1 ? Wr1 : which == 2 ? Wl2 : Wr2;
    _Float16* dst    = which == 0 ? T1l : which == 1 ? T1r : which == 2 ? T2l : T2r;
    int K  = which < 2 ? CIN : F1;
    int Nc = which < 2 ? F1 : F2;
    int tilesN = Nc / 32;
    int tk = (blockIdx.x / tilesN) * 32, tn = (blockIdx.x % tilesN) * 32;
    __shared__ _Float16 tile[32][33];
    int tx = threadIdx.x & 31, ty = threadIdx.x >> 5;
    for (int r = ty; r < 32; r += 8)
        tile[r][tx] = (_Float16)src[(tk + r) * Nc + tn + tx];
    __syncthreads();
    for (int r = ty; r < 32; r += 8)
        dst[(tn + r) * K + tk + tx] = tile[tx][r];
}

// ---------- CSR build (dst in [0,NN)) ----------
__global__ __launch_bounds__(256) void k_hist(const int* __restrict__ ei,
        int* __restrict__ cnt) {
    int i = blockIdx.x * 256 + threadIdx.x;
    atomicAdd(&cnt[ei[E + i]], 1);
}

__global__ __launch_bounds__(256) void k_scan(int* __restrict__ off,
        int* __restrict__ cnt_cur) {
    __shared__ int sc[256];
    int t = threadIdx.x;
    int base = t * 8;
    int local[8];
    int s = 0;
    #pragma unroll
    for (int j = 0; j < 8; ++j) { local[j] = s; s += cnt_cur[base + j]; }
    sc[t] = s;
    __syncthreads();
    for (int o = 1; o < 256; o <<= 1) {
        int v = (t >= o) ? sc[t - o] : 0;
        __syncthreads();
        sc[t] += v;
        __syncthreads();
    }
    int ex = sc[t] - s;
    #pragma unroll
    for (int j = 0; j < 8; ++j) {
        off[base + j] = ex + local[j];
        cnt_cur[base + j] = ex + local[j];
    }
    if (t == 255) off[2048] = sc[255];
}

__global__ __launch_bounds__(256) void k_scatter(const int* __restrict__ ei,
        int* __restrict__ cur, int* __restrict__ srcs) {
    int i = blockIdx.x * 256 + threadIdx.x;
    int d = ei[E + i];
    int pos = atomicAdd(&cur[d], 1);
    srcs[pos] = ei[i];
}

// ---------- K1: temporal embedding GEMM (fp32 VALU, fp32 inputs), writes f16 ----------
__global__ __launch_bounds__(256) void k_temb(const float* __restrict__ in,
        const float* __restrict__ Wt, const float* __restrict__ bt,
        _Float16* __restrict__ xh) {
    constexpr int STR = 36;
    alignas(16) __shared__ float xs[T * STR];
    alignas(16) __shared__ float wsh[T * CIN];
    const int t = threadIdx.x;
    const int tc = t & 31, tr = t >> 5;
    const int row0 = blockIdx.x * 32;
    const int b = row0 / NN, node0 = row0 % NN;
    for (int i = t; i < T * 32; i += 256) {
        int tk = i >> 5, r = i & 31;
        xs[tk * STR + r] = in[(b * T + tk) * NN + node0 + r];
    }
    for (int i = t; i < T * CIN / 4; i += 256)
        ((float4*)wsh)[i] = ((const float4*)Wt)[i];
    __syncthreads();
    float4 acc[4] = {z4(), z4(), z4(), z4()};
    #pragma unroll 4
    for (int k = 0; k < T; ++k) {
        float4 xv = *(const float4*)&xs[k * STR + tr * 4];
        float4 wv = *(const float4*)&wsh[k * CIN + tc * 4];
        fma4(acc[0], xv.x, wv); fma4(acc[1], xv.y, wv);
        fma4(acc[2], xv.z, wv); fma4(acc[3], xv.w, wv);
    }
    float4 bv = *(const float4*)&bt[tc * 4];
    #pragma unroll
    for (int r = 0; r < 4; ++r) {
        float4 o = acc[r];
        f16x4 ov = { (_Float16)(o.x + bv.x), (_Float16)(o.y + bv.y),
                     (_Float16)(o.z + bv.z), (_Float16)(o.w + bv.w) };
        *(f16x4*)&xh[(row0 + tr * 4 + r) * CIN + tc * 4] = ov;
    }
}

// ---------- GM1: dual GEMM, B staged in LDS, 8 waves: mat = wave>>2 in {0,1} ----------
__global__ __launch_bounds__(512) void gm1(const _Float16* __restrict__ Xh,
        const _Float16* __restrict__ BTl, const _Float16* __restrict__ BTr,
        float* __restrict__ xl, float* __restrict__ xr,
        float* __restrict__ acc1, float* __restrict__ dn1) {
    alignas(16) __shared__ _Float16 bs[2 * 256 * KP];  // 40 KB
    const int t = threadIdx.x;
    const int wave = t >> 6, lane = t & 63;
    const int quad = lane >> 4, l15 = lane & 15;
    const int mat = wave >> 2, cg = wave & 3;   // 512 threads = 8 waves
    const int row0 = blockIdx.x * 32;
    f32x4 acc[2][4];
    #pragma unroll
    for (int s = 0; s < 2; ++s)
        #pragma unroll
        for (int c = 0; c < 4; ++c) acc[s][c] = (f32x4){0,0,0,0};
    for (int kt = 0; kt < CIN; kt += 32) {
        if (kt) __syncthreads();
        #pragma unroll
        for (int it = 0; it < 4; ++it) {  // 2 mats x 256 cols x 4 chunks = 2048 items
            int idx = t + it * 512;
            int m = idx >> 10, rem = idx & 1023;
            int col = rem >> 2, j = rem & 3;
            const _Float16* src = (m ? BTr : BTl) + col * CIN + kt + j * 8;
            *(f16x8*)&bs[(m * 256 + col) * KP + j * 8] = *(const f16x8*)src;
        }
        __syncthreads();
        f16x8 af0 = *(const f16x8*)&Xh[(row0 + l15) * CIN + kt + quad * 8];
        f16x8 af1 = *(const f16x8*)&Xh[(row0 + 16 + l15) * CIN + kt + quad * 8];
        #pragma unroll
        for (int ct = 0; ct < 4; ++ct) {
            int col = cg * 64 + ct * 16 + l15;
            f16x8 bf = *(const f16x8*)&bs[(mat * 256 + col) * KP + quad * 8];
            acc[0][ct] = __builtin_amdgcn_mfma_f32_16x16x32_f16(af0, bf, acc[0][ct], 0, 0, 0);
            acc[1][ct] = __builtin_amdgcn_mfma_f32_16x16x32_f16(af1, bf, acc[1][ct], 0, 0, 0);
        }
    }
    if (row0 < NN) {
        float* dst = mat ? xr : xl;
        #pragma unroll
        for (int s = 0; s < 2; ++s)
            #pragma unroll
            for (int ct = 0; ct < 4; ++ct) {
                int col = cg * 64 + ct * 16 + l15;
                #pragma unroll
                for (int r = 0; r < 4; ++r)
                    dst[(row0 + s * 16 + quad * 4 + r) * F1 + col] = acc[s][ct][r];
            }
    } else {
        if (mat == 0) {
            #pragma unroll
            for (int s = 0; s < 2; ++s)
                #pragma unroll
                for (int ct = 0; ct < 4; ++ct) {
                    int col = cg * 64 + ct * 16 + l15;
                    #pragma unroll
                    for (int r = 0; r < 4; ++r)
                        acc1[(row0 + s * 16 + quad * 4 + r) * F1 + col] = acc[s][ct][r];
                }
        }
        if (t < 128) dn1[row0 * H1 + t] = 1.0f;
    }
}

// ---------- gather layer 1 (self-logit computed in-kernel) ----------
__global__ __launch_bounds__(256) void k_gat1(const int* __restrict__ off,
        const int* __restrict__ srcs, const float* __restrict__ xl,
        const float* __restrict__ xr, const float* __restrict__ att,
        float* __restrict__ acc1, float* __restrict__ dn1) {
    const int d = blockIdx.x;
    const int t = threadIdx.x;
    const int wv = t >> 6, c = t & 63;
    const int e0 = off[d], e1 = off[d + 1];
    float b[4], at[4], sh[4], acc[4] = {0,0,0,0}, dnl[4] = {0,0,0,0};
    #pragma unroll
    for (int k = 0; k < 4; ++k) {
        b[k]  = xr[d * F1 + c + 64 * k];
        at[k] = att[c + 64 * k];
        sh[k] = lrelu(xl[d * F1 + c + 64 * k] + b[k]) * at[k];
    }
    #pragma unroll
    for (int o = 32; o; o >>= 1) {
        #pragma unroll
        for (int k = 0; k < 4; ++k) sh[k] += __shfl_xor(sh[k], o, 64);
    }
    for (int e = e0 + wv; e < e1; e += 4) {
        int s = srcs[e];
        float a[4], p[4];
        #pragma unroll
        for (int k = 0; k < 4; ++k) {
            a[k] = xl[s * F1 + c + 64 * k];
            p[k] = lrelu(a[k] + b[k]) * at[k];
        }
        #pragma unroll
        for (int o = 32; o; o >>= 1) {
            #pragma unroll
            for (int k = 0; k < 4; ++k) p[k] += __shfl_xor(p[k], o, 64);
        }
        #pragma unroll
        for (int k = 0; k < 4; ++k) {
            float w = 8.0f * __expf(p[k] - sh[k]);
            dnl[k] += w;
            acc[k] = fmaf(w, a[k], acc[k]);
        }
    }
    __shared__ float lacc[4][F1];
    __shared__ float ldn[4][4];
    #pragma unroll
    for (int k = 0; k < 4; ++k) lacc[wv][c + 64 * k] = acc[k];
    if (c < 4) ldn[wv][c] = dnl[c];
    __syncthreads();
    int f = t;
    float tot = xl[d * F1 + f] + lacc[0][f] + lacc[1][f] + lacc[2][f] + lacc[3][f];
    acc1[d * F1 + f] = tot;
    if (t < 4) dn1[d * H1 + t] = 1.0f + ldn[0][t] + ldn[1][t] + ldn[2][t] + ldn[3][t];
}

// ---------- GM2: dual GEMM K=256, fin fused into A-staging, 8 waves ----------
__global__ __launch_bounds__(512) void gm2(const float* __restrict__ A1,
        const float* __restrict__ dn1, const float* __restrict__ b1,
        const _Float16* __restrict__ BTl, const _Float16* __restrict__ BTr,
        float* __restrict__ xl2, float* __restrict__ xr2,
        float* __restrict__ acc2, float* __restrict__ dn2) {
    alignas(16) __shared__ _Float16 bs[2 * 128 * KP];  // 20 KB
    alignas(16) __shared__ _Float16 as[32 * KP];       // 2.5 KB
    const int t = threadIdx.x;
    const int wave = t >> 6, lane = t & 63;
    const int quad = lane >> 4, l15 = lane & 15;
    const int mat = wave >> 2, cg = wave & 3;   // 512 threads = 8 waves
    const int row0 = blockIdx.x * 32;
    f32x4 acc[2][2];
    #pragma unroll
    for (int s = 0; s < 2; ++s)
        #pragma unroll
        for (int c = 0; c < 2; ++c) acc[s][c] = (f32x4){0,0,0,0};
    for (int kt = 0; kt < F1; kt += 32) {
        if (kt) __syncthreads();
        if (t < 256) {   // A-stage with fused divide/bias/elu -> f16 (32 rows x 8 kc)
            int r = t >> 3, kc = t & 7;
            int node = row0 + r, k0 = kt + kc * 4;
            float4 v = *(const float4*)&A1[node * F1 + k0];
            float rd = 1.0f / (dn1[node * H1 + (k0 >> 6)] + 1e-16f);
            float4 bv = *(const float4*)&b1[k0];
            f16x4 o = { (_Float16)eluf(v.x * rd + bv.x), (_Float16)eluf(v.y * rd + bv.y),
                        (_Float16)eluf(v.z * rd + bv.z), (_Float16)eluf(v.w * rd + bv.w) };
            *(f16x4*)&as[r * KP + kc * 4] = o;
        }
        #pragma unroll
        for (int it = 0; it < 2; ++it) {  // B-stage: 2 mats x 128 cols x 4 chunks = 1024
            int idx = t + it * 512;
            int m = idx >> 9, rem = idx & 511;
            int col = rem >> 2, j = rem & 3;
            const _Float16* src = (m ? BTr : BTl) + col * F1 + kt + j * 8;
            *(f16x8*)&bs[(m * 128 + col) * KP + j * 8] = *(const f16x8*)src;
        }
        __syncthreads();
        f16x8 af0 = *(const f16x8*)&as[l15 * KP + quad * 8];
        f16x8 af1 = *(const f16x8*)&as[(16 + l15) * KP + quad * 8];
        #pragma unroll
        for (int ct = 0; ct < 2; ++ct) {
            int col = cg * 32 + ct * 16 + l15;
            f16x8 bf = *(const f16x8*)&bs[(mat * 128 + col) * KP + quad * 8];
            acc[0][ct] = __builtin_amdgcn_mfma_f32_16x16x32_f16(af0, bf, acc[0][ct], 0, 0, 0);
            acc[1][ct] = __builtin_amdgcn_mfma_f32_16x16x32_f16(af1, bf, acc[1][ct], 0, 0, 0);
        }
    }
    if (row0 < NN) {
        float* dst = mat ? xr2 : xl2;
        #pragma unroll
        for (int s = 0; s < 2; ++s)
            #pragma unroll
            for (int ct = 0; ct < 2; ++ct) {
                int col = cg * 32 + ct * 16 + l15;
                #pragma unroll
                for (int r = 0; r < 4; ++r)
                    dst[(row0 + s * 16 + quad * 4 + r) * F2 + col] = acc[s][ct][r];
            }
    } else {
        if (mat == 0) {
            #pragma unroll
            for (int s = 0; s < 2; ++s)
                #pragma unroll
                for (int ct = 0; ct < 2; ++ct) {
                    int col = cg * 32 + ct * 16 + l15;
                    #pragma unroll
                    for (int r = 0; r < 4; ++r)
                        acc2[(row0 + s * 16 + quad * 4 + r) * F2 + col] = acc[s][ct][r];
                }
        }
        if (t < 32) dn2[row0 + t] = 1.0f;
    }
}

// ---------- gather layer 2 (self-logit in-kernel) ----------
__global__ __launch_bounds__(256) void k_gat2(const int* __restrict__ off,
        const int* __restrict__ srcs, const float* __restrict__ xl,
        const float* __restrict__ xr, const float* __restrict__ att,
        float* __restrict__ acc2, float* __restrict__ dn2) {
    const int d = blockIdx.x;
    const int t = threadIdx.x;
    const int wv = t >> 6, c = t & 63;
    const int e0 = off[d], e1 = off[d + 1];
    float b0 = xr[d * F2 + c], b1v = xr[d * F2 + c + 64];
    float at0 = att[c], at1 = att[c + 64];
    float sh = lrelu(xl[d * F2 + c] + b0) * at0 + lrelu(xl[d * F2 + c + 64] + b1v) * at1;
    #pragma unroll
    for (int o = 32; o; o >>= 1) sh += __shfl_xor(sh, o, 64);
    float acc0 = 0.f, acc1v = 0.f, dnl = 0.f;
    for (int e = e0 + wv; e < e1; e += 4) {
        int s = srcs[e];
        float a0 = xl[s * F2 + c], a1 = xl[s * F2 + c + 64];
        float p = lrelu(a0 + b0) * at0 + lrelu(a1 + b1v) * at1;
        #pragma unroll
        for (int o = 32; o; o >>= 1) p += __shfl_xor(p, o, 64);
        float w = 8.0f * __expf(p - sh);
        dnl += w;
        acc0 = fmaf(w, a0, acc0);
        acc1v = fmaf(w, a1, acc1v);
    }
    __shared__ float lacc[4][F2];
    __shared__ float ldn[4];
    lacc[wv][c] = acc0;
    lacc[wv][c + 64] = acc1v;
    if (c == 0) ldn[wv] = dnl;
    __syncthreads();
    if (t < F2) {
        int f = t;
        acc2[d * F2 + f] = xl[d * F2 + f] + lacc[0][f] + lacc[1][f] + lacc[2][f] + lacc[3][f];
    }
    if (t == 0) dn2[d] = 1.0f + ldn[0] + ldn[1] + ldn[2] + ldn[3];
}

// ---------- batched mean ----------
__global__ __launch_bounds__(128) void k_out(const float* __restrict__ accum,
        const float* __restrict__ dn, const float* __restrict__ b2,
        float* __restrict__ out) {
    int b = blockIdx.x, chunk = blockIdx.y;
    int c = threadIdx.x;
    float acc = 0.f;
    int n0 = b * NN + chunk * 32;
    for (int i = 0; i < 32; ++i) {
        int node = n0 + i;
        acc += accum[node * F2 + c] / (dn[node] + 1e-16f);
    }
    float val = acc * (1.0f / NN);
    if (chunk == 0) val += b2[c];
    atomicAdd(&out[b * F2 + c], val);
}

extern "C" void kernel_launch(void* const* d_in, const int* in_sizes, int n_in,
                              void* d_out, int out_size, void* d_ws, size_t ws_size,
                              hipStream_t stream) {
    const float* in   = (const float*)d_in[0];
    const int*   ei   = (const int*)d_in[1];
    const float* Wt   = (const float*)d_in[2];
    const float* bt   = (const float*)d_in[3];
    const float* Wl1  = (const float*)d_in[4];
    const float* Wr1  = (const float*)d_in[5];
    const float* att1 = (const float*)d_in[6];
    const float* b1   = (const float*)d_in[7];
    const float* Wl2  = (const float*)d_in[8];
    const float* Wr2  = (const float*)d_in[9];
    const float* att2 = (const float*)d_in[10];
    const float* b2   = (const float*)d_in[11];
    float* out = (float*)d_out;

    float* ws = (float*)d_ws;
    _Float16* xh  = (_Float16*)ws;          // N*CIN f16 (4 MB)
    float* xl1  = (float*)(xh + N * CIN);   // NN*F1 (2 MB)
    float* xr1  = xl1 + NN * F1;            // NN*F1
    float* acc1 = xr1 + NN * F1;            // N*F1 (16 MB)
    float* dn1  = acc1 + N * F1;            // N*H1
    float* xl2  = dn1 + N * H1;             // NN*F2
    float* xr2  = xl2 + NN * F2;            // NN*F2
    float* acc2 = xr2 + NN * F2;            // N*F2 (8 MB)
    float* dn2  = acc2 + N * F2;            // N
    _Float16* T1l = (_Float16*)(dn2 + N);   // 256*128
    _Float16* T1r = T1l + 256 * 128;
    _Float16* T2l = T1r + 256 * 128;        // 128*256
    _Float16* T2r = T2l + 128 * 256;
    int* off  = (int*)(T2r + 128 * 256);    // NN+1
    int* cur  = off + (NN + 1);             // NN
    int* srcs = cur + NN;                   // E

    hipMemsetAsync(d_out, 0, (size_t)out_size * sizeof(float), stream);
    hipMemsetAsync(cur, 0, NN * sizeof(int), stream);

    k_wt<<<dim3(32, 4), 256, 0, stream>>>(Wl1, Wr1, Wl2, Wr2, T1l, T1r, T2l, T2r);
    k_hist<<<E / 256, 256, 0, stream>>>(ei, cur);
    k_scan<<<1, 256, 0, stream>>>(off, cur);
    k_scatter<<<E / 256, 256, 0, stream>>>(ei, cur, srcs);
    k_temb<<<N / 32, 256, 0, stream>>>(in, Wt, bt, xh);
    gm1<<<N / 32, 512, 0, stream>>>(xh, T1l, T1r, xl1, xr1, acc1, dn1);
    k_gat1<<<NN, 256, 0, stream>>>(off, srcs, xl1, xr1, att1, acc1, dn1);
    gm2<<<N / 32, 512, 0, stream>>>(acc1, dn1, b1, T2l, T2r, xl2, xr2, acc2, dn2);
    k_gat2<<<NN, 256, 0, stream>>>(off, srcs, xl2, xr2, att2, acc2, dn2);
    k_out<<<dim3(BSZ, 64), 128, 0, stream>>>(acc2, dn2, b2, out);
}

// Round 10
// 168.208 us; speedup vs baseline: 1.6443x; 1.0211x over previous
//
#include <hip/hip_runtime.h>
#include <hip/hip_bf16.h>
#include <math.h>

#define NEG_SLOPE 0.2f

constexpr int BSZ = 8, T = 100, NN = 2048, N = BSZ * NN; // N = 16384
constexpr int CIN = 128, H1 = 4, F1 = 256, F2 = 128;
constexpr int E = 32768;
constexpr int KP = 40;  // padded LDS inner dim (f16) to break bank conflicts

typedef _Float16 f16x8 __attribute__((ext_vector_type(8)));
typedef _Float16 f16x4 __attribute__((ext_vector_type(4)));
typedef float f32x4 __attribute__((ext_vector_type(4)));

__device__ inline float lrelu(float m) { return m > 0.f ? m : NEG_SLOPE * m; }
__device__ inline float eluf(float v) { return v > 0.f ? v : expm1f(v); }

// ---------- weight transpose + f16 convert (+K-pad for W_temb) ----------
// which: 0 Wt(100->128,128)  1 Wl1(128,256)  2 Wr1  3 Wl2(256,128)  4 Wr2
__global__ __launch_bounds__(256) void k_wt(const float* __restrict__ Wt,
        const float* __restrict__ Wl1, const float* __restrict__ Wr1,
        const float* __restrict__ Wl2, const float* __restrict__ Wr2,
        _Float16* __restrict__ Tt, _Float16* __restrict__ T1l,
        _Float16* __restrict__ T1r, _Float16* __restrict__ T2l,
        _Float16* __restrict__ T2r) {
    const int which = blockIdx.y;
    const int Ks[5] = {100, 128, 128, 256, 256};
    const int Kd[5] = {128, 128, 128, 256, 256};
    const int Nc[5] = {128, 256, 256, 128, 128};
    const float* srcs[5] = {Wt, Wl1, Wr1, Wl2, Wr2};
    _Float16* dsts[5] = {Tt, T1l, T1r, T2l, T2r};
    int ks = Ks[which], kd = Kd[which], nc = Nc[which];
    int tilesN = nc / 32;
    int tiles = (kd / 32) * tilesN;
    if (blockIdx.x >= (unsigned)tiles) return;
    int tk = (blockIdx.x / tilesN) * 32, tn = (blockIdx.x % tilesN) * 32;
    const float* src = srcs[which];
    _Float16* dst = dsts[which];
    __shared__ _Float16 tile[32][33];
    int tx = threadIdx.x & 31, ty = threadIdx.x >> 5;
    for (int r = ty; r < 32; r += 8)
        tile[r][tx] = (tk + r < ks) ? (_Float16)src[(tk + r) * nc + tn + tx] : (_Float16)0.f;
    __syncthreads();
    for (int r = ty; r < 32; r += 8)
        dst[(tn + r) * kd + tk + tx] = tile[tx][r];
}

// ---------- input transpose+convert: xTh[b*NN+node][k] = f16 in[b][k][node], k<100 ----------
__global__ __launch_bounds__(256) void k_cvt(const float* __restrict__ in,
        _Float16* __restrict__ xTh) {
    __shared__ float lt[T * 65];
    const int b = blockIdx.y, node0 = blockIdx.x * 64;
    const int t = threadIdx.x;
    for (int i = t; i < T * 64; i += 256) {
        int tt = i >> 6, n = i & 63;
        lt[tt * 65 + n] = in[(b * T + tt) * NN + node0 + n];
    }
    __syncthreads();
    const int node = t >> 2, seg = t & 3;
    _Float16* dst = &xTh[(b * NN + node0 + node) * 128 + seg * 32];
    #pragma unroll
    for (int j = 0; j < 4; ++j) {
        f16x8 v;
        #pragma unroll
        for (int e = 0; e < 8; ++e) {
            int k = seg * 32 + j * 8 + e;
            v[e] = (k < T) ? (_Float16)lt[k * 65 + node] : (_Float16)0.f;
        }
        *(f16x8*)&dst[j * 8] = v;
    }
}

// ---------- CSR build (dst in [0,NN)) ----------
__global__ __launch_bounds__(256) void k_hist(const int* __restrict__ ei,
        int* __restrict__ cnt) {
    int i = blockIdx.x * 256 + threadIdx.x;
    atomicAdd(&cnt[ei[E + i]], 1);
}

__global__ __launch_bounds__(256) void k_scan(int* __restrict__ off,
        int* __restrict__ cnt_cur) {
    __shared__ int sc[256];
    int t = threadIdx.x;
    int base = t * 8;
    int local[8];
    int s = 0;
    #pragma unroll
    for (int j = 0; j < 8; ++j) { local[j] = s; s += cnt_cur[base + j]; }
    sc[t] = s;
    __syncthreads();
    for (int o = 1; o < 256; o <<= 1) {
        int v = (t >= o) ? sc[t - o] : 0;
        __syncthreads();
        sc[t] += v;
        __syncthreads();
    }
    int ex = sc[t] - s;
    #pragma unroll
    for (int j = 0; j < 8; ++j) {
        off[base + j] = ex + local[j];
        cnt_cur[base + j] = ex + local[j];
    }
    if (t == 255) off[2048] = sc[255];
}

__global__ __launch_bounds__(256) void k_scatter(const int* __restrict__ ei,
        int* __restrict__ cur, int* __restrict__ srcs) {
    int i = blockIdx.x * 256 + threadIdx.x;
    int d = ei[E + i];
    int pos = atomicAdd(&cur[d], 1);
    srcs[pos] = ei[i];
}

// ---------- GMT: temb GEMM via MFMA. xh f16 = xTh @ Tt^T + bt ----------
__global__ __launch_bounds__(256) void gmt(const _Float16* __restrict__ Xh,
        const _Float16* __restrict__ BT, const float* __restrict__ bt,
        _Float16* __restrict__ xh) {
    alignas(16) __shared__ _Float16 bs[128 * KP];  // 10 KB
    const int t = threadIdx.x;
    const int wave = t >> 6, lane = t & 63;
    const int quad = lane >> 4, l15 = lane & 15;
    const int row0 = blockIdx.x * 32;
    f32x4 acc[2][2];
    #pragma unroll
    for (int s = 0; s < 2; ++s)
        #pragma unroll
        for (int c = 0; c < 2; ++c) acc[s][c] = (f32x4){0,0,0,0};
    for (int kt = 0; kt < 128; kt += 32) {
        if (kt) __syncthreads();
        #pragma unroll
        for (int it = 0; it < 2; ++it) {  // 128 cols x 4 chunks
            int idx = t + it * 256;
            int col = idx >> 2, j = idx & 3;
            *(f16x8*)&bs[col * KP + j * 8] = *(const f16x8*)&BT[col * 128 + kt + j * 8];
        }
        __syncthreads();
        f16x8 af0 = *(const f16x8*)&Xh[(row0 + l15) * 128 + kt + quad * 8];
        f16x8 af1 = *(const f16x8*)&Xh[(row0 + 16 + l15) * 128 + kt + quad * 8];
        #pragma unroll
        for (int ct = 0; ct < 2; ++ct) {
            int col = wave * 32 + ct * 16 + l15;   // 4 waves x 32 = 128 cols
            f16x8 bf = *(const f16x8*)&bs[col * KP + quad * 8];
            acc[0][ct] = __builtin_amdgcn_mfma_f32_16x16x32_f16(af0, bf, acc[0][ct], 0, 0, 0);
            acc[1][ct] = __builtin_amdgcn_mfma_f32_16x16x32_f16(af1, bf, acc[1][ct], 0, 0, 0);
        }
    }
    #pragma unroll
    for (int ct = 0; ct < 2; ++ct) {
        int col = wave * 32 + ct * 16 + l15;
        float bv = bt[col];
        #pragma unroll
        for (int s = 0; s < 2; ++s)
            #pragma unroll
            for (int r = 0; r < 4; ++r)
                xh[(row0 + s * 16 + quad * 4 + r) * CIN + col] = (_Float16)(acc[s][ct][r] + bv);
    }
}

// ---------- GM1: dual GEMM, B staged in LDS, 8 waves: mat = wave>>2 in {0,1} ----------
__global__ __launch_bounds__(512) void gm1(const _Float16* __restrict__ Xh,
        const _Float16* __restrict__ BTl, const _Float16* __restrict__ BTr,
        float* __restrict__ xl, float* __restrict__ xr,
        float* __restrict__ acc1, float* __restrict__ dn1) {
    alignas(16) __shared__ _Float16 bs[2 * 256 * KP];  // 40 KB
    const int t = threadIdx.x;
    const int wave = t >> 6, lane = t & 63;
    const int quad = lane >> 4, l15 = lane & 15;
    const int mat = wave >> 2, cg = wave & 3;   // 512 threads = 8 waves
    const int row0 = blockIdx.x * 32;
    f32x4 acc[2][4];
    #pragma unroll
    for (int s = 0; s < 2; ++s)
        #pragma unroll
        for (int c = 0; c < 4; ++c) acc[s][c] = (f32x4){0,0,0,0};
    for (int kt = 0; kt < CIN; kt += 32) {
        if (kt) __syncthreads();
        #pragma unroll
        for (int it = 0; it < 4; ++it) {  // 2 mats x 256 cols x 4 chunks = 2048 items
            int idx = t + it * 512;
            int m = idx >> 10, rem = idx & 1023;
            int col = rem >> 2, j = rem & 3;
            const _Float16* src = (m ? BTr : BTl) + col * CIN + kt + j * 8;
            *(f16x8*)&bs[(m * 256 + col) * KP + j * 8] = *(const f16x8*)src;
        }
        __syncthreads();
        f16x8 af0 = *(const f16x8*)&Xh[(row0 + l15) * CIN + kt + quad * 8];
        f16x8 af1 = *(const f16x8*)&Xh[(row0 + 16 + l15) * CIN + kt + quad * 8];
        #pragma unroll
        for (int ct = 0; ct < 4; ++ct) {
            int col = cg * 64 + ct * 16 + l15;
            f16x8 bf = *(const f16x8*)&bs[(mat * 256 + col) * KP + quad * 8];
            acc[0][ct] = __builtin_amdgcn_mfma_f32_16x16x32_f16(af0, bf, acc[0][ct], 0, 0, 0);
            acc[1][ct] = __builtin_amdgcn_mfma_f32_16x16x32_f16(af1, bf, acc[1][ct], 0, 0, 0);
        }
    }
    if (row0 < NN) {
        float* dst = mat ? xr : xl;
        #pragma unroll
        for (int s = 0; s < 2; ++s)
            #pragma unroll
            for (int ct = 0; ct < 4; ++ct) {
                int col = cg * 64 + ct * 16 + l15;
                #pragma unroll
                for (int r = 0; r < 4; ++r)
                    dst[(row0 + s * 16 + quad * 4 + r) * F1 + col] = acc[s][ct][r];
            }
    } else {
        if (mat == 0) {
            #pragma unroll
            for (int s = 0; s < 2; ++s)
                #pragma unroll
                for (int ct = 0; ct < 4; ++ct) {
                    int col = cg * 64 + ct * 16 + l15;
                    #pragma unroll
                    for (int r = 0; r < 4; ++r)
                        acc1[(row0 + s * 16 + quad * 4 + r) * F1 + col] = acc[s][ct][r];
                }
        }
        if (t < 128) dn1[row0 * H1 + t] = 1.0f;
    }
}

// ---------- gather layer 1 (self-logit computed in-kernel) ----------
__global__ __launch_bounds__(256) void k_gat1(const int* __restrict__ off,
        const int* __restrict__ srcs, const float* __restrict__ xl,
        const float* __restrict__ xr, const float* __restrict__ att,
        float* __restrict__ acc1, float* __restrict__ dn1) {
    const int d = blockIdx.x;
    const int t = threadIdx.x;
    const int wv = t >> 6, c = t & 63;
    const int e0 = off[d], e1 = off[d + 1];
    float b[4], at[4], sh[4], acc[4] = {0,0,0,0}, dnl[4] = {0,0,0,0};
    #pragma unroll
    for (int k = 0; k < 4; ++k) {
        b[k]  = xr[d * F1 + c + 64 * k];
        at[k] = att[c + 64 * k];
        sh[k] = lrelu(xl[d * F1 + c + 64 * k] + b[k]) * at[k];
    }
    #pragma unroll
    for (int o = 32; o; o >>= 1) {
        #pragma unroll
        for (int k = 0; k < 4; ++k) sh[k] += __shfl_xor(sh[k], o, 64);
    }
    for (int e = e0 + wv; e < e1; e += 4) {
        int s = srcs[e];
        float a[4], p[4];
        #pragma unroll
        for (int k = 0; k < 4; ++k) {
            a[k] = xl[s * F1 + c + 64 * k];
            p[k] = lrelu(a[k] + b[k]) * at[k];
        }
        #pragma unroll
        for (int o = 32; o; o >>= 1) {
            #pragma unroll
            for (int k = 0; k < 4; ++k) p[k] += __shfl_xor(p[k], o, 64);
        }
        #pragma unroll
        for (int k = 0; k < 4; ++k) {
            float w = 8.0f * __expf(p[k] - sh[k]);
            dnl[k] += w;
            acc[k] = fmaf(w, a[k], acc[k]);
        }
    }
    __shared__ float lacc[4][F1];
    __shared__ float ldn[4][4];
    #pragma unroll
    for (int k = 0; k < 4; ++k) lacc[wv][c + 64 * k] = acc[k];
    if (c < 4) ldn[wv][c] = dnl[c];
    __syncthreads();
    int f = t;
    float tot = xl[d * F1 + f] + lacc[0][f] + lacc[1][f] + lacc[2][f] + lacc[3][f];
    acc1[d * F1 + f] = tot;
    if (t < 4) dn1[d * H1 + t] = 1.0f + ldn[0][t] + ldn[1][t] + ldn[2][t] + ldn[3][t];
}

// ---------- GM2: dual GEMM K=256, fin fused into A-staging, 8 waves ----------
__global__ __launch_bounds__(512) void gm2(const float* __restrict__ A1,
        const float* __restrict__ dn1, const float* __restrict__ b1,
        const _Float16* __restrict__ BTl, const _Float16* __restrict__ BTr,
        float* __restrict__ xl2, float* __restrict__ xr2,
        float* __restrict__ acc2, float* __restrict__ dn2) {
    alignas(16) __shared__ _Float16 bs[2 * 128 * KP];  // 20 KB
    alignas(16) __shared__ _Float16 as[32 * KP];       // 2.5 KB
    const int t = threadIdx.x;
    const int wave = t >> 6, lane = t & 63;
    const int quad = lane >> 4, l15 = lane & 15;
    const int mat = wave >> 2, cg = wave & 3;   // 512 threads = 8 waves
    const int row0 = blockIdx.x * 32;
    f32x4 acc[2][2];
    #pragma unroll
    for (int s = 0; s < 2; ++s)
        #pragma unroll
        for (int c = 0; c < 2; ++c) acc[s][c] = (f32x4){0,0,0,0};
    for (int kt = 0; kt < F1; kt += 32) {
        if (kt) __syncthreads();
        if (t < 256) {   // A-stage with fused divide/bias/elu -> f16 (32 rows x 8 kc)
            int r = t >> 3, kc = t & 7;
            int node = row0 + r, k0 = kt + kc * 4;
            float4 v = *(const float4*)&A1[node * F1 + k0];
            float rd = 1.0f / (dn1[node * H1 + (k0 >> 6)] + 1e-16f);
            float4 bv = *(const float4*)&b1[k0];
            f16x4 o = { (_Float16)eluf(v.x * rd + bv.x), (_Float16)eluf(v.y * rd + bv.y),
                        (_Float16)eluf(v.z * rd + bv.z), (_Float16)eluf(v.w * rd + bv.w) };
            *(f16x4*)&as[r * KP + kc * 4] = o;
        }
        #pragma unroll
        for (int it = 0; it < 2; ++it) {  // B-stage: 2 mats x 128 cols x 4 chunks = 1024
            int idx = t + it * 512;
            int m = idx >> 9, rem = idx & 511;
            int col = rem >> 2, j = rem & 3;
            const _Float16* src = (m ? BTr : BTl) + col * F1 + kt + j * 8;
            *(f16x8*)&bs[(m * 128 + col) * KP + j * 8] = *(const f16x8*)src;
        }
        __syncthreads();
        f16x8 af0 = *(const f16x8*)&as[l15 * KP + quad * 8];
        f16x8 af1 = *(const f16x8*)&as[(16 + l15) * KP + quad * 8];
        #pragma unroll
        for (int ct = 0; ct < 2; ++ct) {
            int col = cg * 32 + ct * 16 + l15;
            f16x8 bf = *(const f16x8*)&bs[(mat * 128 + col) * KP + quad * 8];
            acc[0][ct] = __builtin_amdgcn_mfma_f32_16x16x32_f16(af0, bf, acc[0][ct], 0, 0, 0);
            acc[1][ct] = __builtin_amdgcn_mfma_f32_16x16x32_f16(af1, bf, acc[1][ct], 0, 0, 0);
        }
    }
    if (row0 < NN) {
        float* dst = mat ? xr2 : xl2;
        #pragma unroll
        for (int s = 0; s < 2; ++s)
            #pragma unroll
            for (int ct = 0; ct < 2; ++ct) {
                int col = cg * 32 + ct * 16 + l15;
                #pragma unroll
                for (int r = 0; r < 4; ++r)
                    dst[(row0 + s * 16 + quad * 4 + r) * F2 + col] = acc[s][ct][r];
            }
    } else {
        if (mat == 0) {
            #pragma unroll
            for (int s = 0; s < 2; ++s)
                #pragma unroll
                for (int ct = 0; ct < 2; ++ct) {
                    int col = cg * 32 + ct * 16 + l15;
                    #pragma unroll
                    for (int r = 0; r < 4; ++r)
                        acc2[(row0 + s * 16 + quad * 4 + r) * F2 + col] = acc[s][ct][r];
                }
        }
        if (t < 32) dn2[row0 + t] = 1.0f;
    }
}

// ---------- gather layer 2 (self-logit in-kernel) ----------
__global__ __launch_bounds__(256) void k_gat2(const int* __restrict__ off,
        const int* __restrict__ srcs, const float* __restrict__ xl,
        const float* __restrict__ xr, const float* __restrict__ att,
        float* __restrict__ acc2, float* __restrict__ dn2) {
    const int d = blockIdx.x;
    const int t = threadIdx.x;
    const int wv = t >> 6, c = t & 63;
    const int e0 = off[d], e1 = off[d + 1];
    float b0 = xr[d * F2 + c], b1v = xr[d * F2 + c + 64];
    float at0 = att[c], at1 = att[c + 64];
    float sh = lrelu(xl[d * F2 + c] + b0) * at0 + lrelu(xl[d * F2 + c + 64] + b1v) * at1;
    #pragma unroll
    for (int o = 32; o; o >>= 1) sh += __shfl_xor(sh, o, 64);
    float acc0 = 0.f, acc1v = 0.f, dnl = 0.f;
    for (int e = e0 + wv; e < e1; e += 4) {
        int s = srcs[e];
        float a0 = xl[s * F2 + c], a1 = xl[s * F2 + c + 64];
        float p = lrelu(a0 + b0) * at0 + lrelu(a1 + b1v) * at1;
        #pragma unroll
        for (int o = 32; o; o >>= 1) p += __shfl_xor(p, o, 64);
        float w = 8.0f * __expf(p - sh);
        dnl += w;
        acc0 = fmaf(w, a0, acc0);
        acc1v = fmaf(w, a1, acc1v);
    }
    __shared__ float lacc[4][F2];
    __shared__ float ldn[4];
    lacc[wv][c] = acc0;
    lacc[wv][c + 64] = acc1v;
    if (c == 0) ldn[wv] = dnl;
    __syncthreads();
    if (t < F2) {
        int f = t;
        acc2[d * F2 + f] = xl[d * F2 + f] + lacc[0][f] + lacc[1][f] + lacc[2][f] + lacc[3][f];
    }
    if (t == 0) dn2[d] = 1.0f + ldn[0] + ldn[1] + ldn[2] + ldn[3];
}

// ---------- batched mean ----------
__global__ __launch_bounds__(128) void k_out(const float* __restrict__ accum,
        const float* __restrict__ dn, const float* __restrict__ b2,
        float* __restrict__ out) {
    int b = blockIdx.x, chunk = blockIdx.y;
    int c = threadIdx.x;
    float acc = 0.f;
    int n0 = b * NN + chunk * 32;
    for (int i = 0; i < 32; ++i) {
        int node = n0 + i;
        acc += accum[node * F2 + c] / (dn[node] + 1e-16f);
    }
    float val = acc * (1.0f / NN);
    if (chunk == 0) val += b2[c];
    atomicAdd(&out[b * F2 + c], val);
}

extern "C" void kernel_launch(void* const* d_in, const int* in_sizes, int n_in,
                              void* d_out, int out_size, void* d_ws, size_t ws_size,
                              hipStream_t stream) {
    const float* in   = (const float*)d_in[0];
    const int*   ei   = (const int*)d_in[1];
    const float* Wt   = (const float*)d_in[2];
    const float* bt   = (const float*)d_in[3];
    const float* Wl1  = (const float*)d_in[4];
    const float* Wr1  = (const float*)d_in[5];
    const float* att1 = (const float*)d_in[6];
    const float* b1   = (const float*)d_in[7];
    const float* Wl2  = (const float*)d_in[8];
    const float* Wr2  = (const float*)d_in[9];
    const float* att2 = (const float*)d_in[10];
    const float* b2   = (const float*)d_in[11];
    float* out = (float*)d_out;

    float* ws = (float*)d_ws;
    _Float16* xTh = (_Float16*)ws;          // N*128 f16 (4 MB)
    _Float16* xh  = xTh + N * 128;          // N*CIN f16 (4 MB)
    float* xl1  = (float*)(xh + N * CIN);   // NN*F1 (2 MB)
    float* xr1  = xl1 + NN * F1;            // NN*F1
    float* acc1 = xr1 + NN * F1;            // N*F1 (16 MB)
    float* dn1  = acc1 + N * F1;            // N*H1
    float* xl2  = dn1 + N * H1;             // NN*F2
    float* xr2  = xl2 + NN * F2;            // NN*F2
    float* acc2 = xr2 + NN * F2;            // N*F2 (8 MB)
    float* dn2  = acc2 + N * F2;            // N
    _Float16* Tt  = (_Float16*)(dn2 + N);   // 128*128
    _Float16* T1l = Tt + 128 * 128;         // 256*128
    _Float16* T1r = T1l + 256 * 128;
    _Float16* T2l = T1r + 256 * 128;        // 128*256
    _Float16* T2r = T2l + 128 * 256;
    int* off  = (int*)(T2r + 128 * 256);    // NN+1
    int* cur  = off + (NN + 1);             // NN
    int* srcs = cur + NN;                   // E

    hipMemsetAsync(d_out, 0, (size_t)out_size * sizeof(float), stream);
    hipMemsetAsync(cur, 0, NN * sizeof(int), stream);

    k_wt<<<dim3(32, 5), 256, 0, stream>>>(Wt, Wl1, Wr1, Wl2, Wr2, Tt, T1l, T1r, T2l, T2r);
    k_cvt<<<dim3(NN / 64, BSZ), 256, 0, stream>>>(in, xTh);
    k_hist<<<E / 256, 256, 0, stream>>>(ei, cur);
    k_scan<<<1, 256, 0, stream>>>(off, cur);
    k_scatter<<<E / 256, 256, 0, stream>>>(ei, cur, srcs);
    gmt<<<N / 32, 256, 0, stream>>>(xTh, Tt, bt, xh);
    gm1<<<N / 32, 512, 0, stream>>>(xh, T1l, T1r, xl1, xr1, acc1, dn1);
    k_gat1<<<NN, 256, 0, stream>>>(off, srcs, xl1, xr1, att1, acc1, dn1);
    gm2<<<N / 32, 512, 0, stream>>>(acc1, dn1, b1, T2l, T2r, xl2, xr2, acc2, dn2);
    k_gat2<<<NN, 256, 0, stream>>>(off, srcs, xl2, xr2, att2, acc2, dn2);
    k_out<<<dim3(BSZ, 64), 128, 0, stream>>>(acc2, dn2, b2, out);
}

// Round 11
// 150.871 us; speedup vs baseline: 1.8333x; 1.1149x over previous
//
#include <hip/hip_runtime.h>
#include <hip/hip_bf16.h>
#include <math.h>

#define NEG_SLOPE 0.2f

constexpr int BSZ = 8, T = 100, NN = 2048, N = BSZ * NN; // N = 16384
constexpr int CIN = 128, H1 = 4, F1 = 256, F2 = 128;
constexpr int E = 32768;
constexpr int KP = 40;  // padded LDS inner dim (f16) to break bank conflicts

typedef _Float16 f16x8 __attribute__((ext_vector_type(8)));
typedef _Float16 f16x4 __attribute__((ext_vector_type(4)));
typedef float f32x4 __attribute__((ext_vector_type(4)));

__device__ inline float lrelu(float m) { return m > 0.f ? m : NEG_SLOPE * m; }
__device__ inline float eluf(float v) { return v > 0.f ? v : expm1f(v); }

// ===== L1: weight transposes (+f16, +K-pad) AND zero cur/out =====
// y: 0 Wt(100->128,128) 1 Wl1(128,256) 2 Wr1 3 Wl2(256,128) 4 Wr2 5 zeros
__global__ __launch_bounds__(256) void k_prep(const float* __restrict__ Wt,
        const float* __restrict__ Wl1, const float* __restrict__ Wr1,
        const float* __restrict__ Wl2, const float* __restrict__ Wr2,
        _Float16* __restrict__ Tt, _Float16* __restrict__ T1l,
        _Float16* __restrict__ T1r, _Float16* __restrict__ T2l,
        _Float16* __restrict__ T2r, int* __restrict__ cur, float* __restrict__ out) {
    const int which = blockIdx.y;
    const int t = threadIdx.x;
    if (which == 5) {
        if (blockIdx.x == 0) {
            for (int i = t; i < NN; i += 256) cur[i] = 0;
            for (int i = t; i < BSZ * F2; i += 256) out[i] = 0.f;
        }
        return;
    }
    const int Ks[5] = {100, 128, 128, 256, 256};
    const int Kd[5] = {128, 128, 128, 256, 256};
    const int Nc[5] = {128, 256, 256, 128, 128};
    const float* srcs[5] = {Wt, Wl1, Wr1, Wl2, Wr2};
    _Float16* dsts[5] = {Tt, T1l, T1r, T2l, T2r};
    int ks = Ks[which], kd = Kd[which], nc = Nc[which];
    int tilesN = nc / 32;
    int tiles = (kd / 32) * tilesN;
    if (blockIdx.x >= (unsigned)tiles) return;
    int tk = (blockIdx.x / tilesN) * 32, tn = (blockIdx.x % tilesN) * 32;
    const float* src = srcs[which];
    _Float16* dst = dsts[which];
    __shared__ _Float16 tile[32][33];
    int tx = t & 31, ty = t >> 5;
    for (int r = ty; r < 32; r += 8)
        tile[r][tx] = (tk + r < ks) ? (_Float16)src[(tk + r) * nc + tn + tx] : (_Float16)0.f;
    __syncthreads();
    for (int r = ty; r < 32; r += 8)
        dst[(tn + r) * kd + tk + tx] = tile[tx][r];
}

// ===== L2: input transpose+f16 (y<8) AND edge histogram (y==8) =====
__global__ __launch_bounds__(256) void k_cvt_hist(const float* __restrict__ in,
        _Float16* __restrict__ xTh, const int* __restrict__ ei, int* __restrict__ cnt) {
    const int t = threadIdx.x;
    if (blockIdx.y == 8) {
        int i = blockIdx.x * 256 + t;   // x < 128
        atomicAdd(&cnt[ei[E + i]], 1);
        return;
    }
    if (blockIdx.x >= 32) return;
    __shared__ float lt[T * 65];
    const int b = blockIdx.y, node0 = blockIdx.x * 64;
    for (int i = t; i < T * 64; i += 256) {
        int tt = i >> 6, n = i & 63;
        lt[tt * 65 + n] = in[(b * T + tt) * NN + node0 + n];
    }
    __syncthreads();
    const int node = t >> 2, seg = t & 3;
    _Float16* dst = &xTh[(b * NN + node0 + node) * 128 + seg * 32];
    #pragma unroll
    for (int j = 0; j < 4; ++j) {
        f16x8 v;
        #pragma unroll
        for (int e = 0; e < 8; ++e) {
            int k = seg * 32 + j * 8 + e;
            v[e] = (k < T) ? (_Float16)lt[k * 65 + node] : (_Float16)0.f;
        }
        *(f16x8*)&dst[j * 8] = v;
    }
}

// ===== L3: CSR scan (x==512) AND temb MFMA GEMM (x<512) =====
__global__ __launch_bounds__(256) void k_scan_gmt(int* __restrict__ off,
        int* __restrict__ cnt_cur, const _Float16* __restrict__ Xh,
        const _Float16* __restrict__ BT, const float* __restrict__ bt,
        _Float16* __restrict__ xh) {
    const int t = threadIdx.x;
    if (blockIdx.x == 512) {   // exclusive scan of 2048 counts
        __shared__ int sc[256];
        int base = t * 8;
        int local[8];
        int s = 0;
        #pragma unroll
        for (int j = 0; j < 8; ++j) { local[j] = s; s += cnt_cur[base + j]; }
        sc[t] = s;
        __syncthreads();
        for (int o = 1; o < 256; o <<= 1) {
            int v = (t >= o) ? sc[t - o] : 0;
            __syncthreads();
            sc[t] += v;
            __syncthreads();
        }
        int ex = sc[t] - s;
        #pragma unroll
        for (int j = 0; j < 8; ++j) {
            off[base + j] = ex + local[j];
            cnt_cur[base + j] = ex + local[j];
        }
        if (t == 255) off[2048] = sc[255];
        return;
    }
    // temb GEMM: xh = xTh @ Tt^T + bt
    alignas(16) __shared__ _Float16 bs[128 * KP];
    const int wave = t >> 6, lane = t & 63;
    const int quad = lane >> 4, l15 = lane & 15;
    const int row0 = blockIdx.x * 32;
    f32x4 acc[2][2];
    #pragma unroll
    for (int s = 0; s < 2; ++s)
        #pragma unroll
        for (int c = 0; c < 2; ++c) acc[s][c] = (f32x4){0,0,0,0};
    for (int kt = 0; kt < 128; kt += 32) {
        if (kt) __syncthreads();
        #pragma unroll
        for (int it = 0; it < 2; ++it) {
            int idx = t + it * 256;
            int col = idx >> 2, j = idx & 3;
            *(f16x8*)&bs[col * KP + j * 8] = *(const f16x8*)&BT[col * 128 + kt + j * 8];
        }
        __syncthreads();
        f16x8 af0 = *(const f16x8*)&Xh[(row0 + l15) * 128 + kt + quad * 8];
        f16x8 af1 = *(const f16x8*)&Xh[(row0 + 16 + l15) * 128 + kt + quad * 8];
        #pragma unroll
        for (int ct = 0; ct < 2; ++ct) {
            int col = wave * 32 + ct * 16 + l15;
            f16x8 bf = *(const f16x8*)&bs[col * KP + quad * 8];
            acc[0][ct] = __builtin_amdgcn_mfma_f32_16x16x32_f16(af0, bf, acc[0][ct], 0, 0, 0);
            acc[1][ct] = __builtin_amdgcn_mfma_f32_16x16x32_f16(af1, bf, acc[1][ct], 0, 0, 0);
        }
    }
    #pragma unroll
    for (int ct = 0; ct < 2; ++ct) {
        int col = wave * 32 + ct * 16 + l15;
        float bv = bt[col];
        #pragma unroll
        for (int s = 0; s < 2; ++s)
            #pragma unroll
            for (int r = 0; r < 4; ++r)
                xh[(row0 + s * 16 + quad * 4 + r) * CIN + col] = (_Float16)(acc[s][ct][r] + bv);
    }
}

// ===== L4: CSR scatter (x>=512) AND layer-1 dual MFMA GEMM (x<512) =====
// gm1: rows<NN -> xl/xr fp32; rows>=NN -> h1h = f16 elu(aL + b1) (self-only nodes)
__global__ __launch_bounds__(512) void k_scat_gm1(const int* __restrict__ ei,
        int* __restrict__ cur, int* __restrict__ srcs4,
        const _Float16* __restrict__ Xh, const _Float16* __restrict__ BTl,
        const _Float16* __restrict__ BTr, const float* __restrict__ b1,
        float* __restrict__ xl, float* __restrict__ xr, _Float16* __restrict__ h1h) {
    const int t = threadIdx.x;
    if (blockIdx.x >= 512) {
        int i = (blockIdx.x - 512) * 512 + t;   // 64 blocks x 512 = E
        int d = ei[E + i];
        int pos = atomicAdd(&cur[d], 1);
        srcs4[pos] = ei[i];
        return;
    }
    alignas(16) __shared__ _Float16 bs[2 * 256 * KP];  // 40 KB
    const int wave = t >> 6, lane = t & 63;
    const int quad = lane >> 4, l15 = lane & 15;
    const int mat = wave >> 2, cg = wave & 3;
    const int row0 = blockIdx.x * 32;
    const int nmats = (row0 < NN) ? 2 : 1;   // self-only rows need just Wl
    f32x4 acc[2][4];
    #pragma unroll
    for (int s = 0; s < 2; ++s)
        #pragma unroll
        for (int c = 0; c < 4; ++c) acc[s][c] = (f32x4){0,0,0,0};
    for (int kt = 0; kt < CIN; kt += 32) {
        if (kt) __syncthreads();
        for (int it = 0; it < nmats * 2; ++it) {  // nmats x 256 cols x 4 chunks
            int idx = t + it * 512;
            int m = idx >> 10, rem = idx & 1023;
            int col = rem >> 2, j = rem & 3;
            const _Float16* src = (m ? BTr : BTl) + col * CIN + kt + j * 8;
            *(f16x8*)&bs[(m * 256 + col) * KP + j * 8] = *(const f16x8*)src;
        }
        __syncthreads();
        if (mat < nmats) {
            f16x8 af0 = *(const f16x8*)&Xh[(row0 + l15) * CIN + kt + quad * 8];
            f16x8 af1 = *(const f16x8*)&Xh[(row0 + 16 + l15) * CIN + kt + quad * 8];
            #pragma unroll
            for (int ct = 0; ct < 4; ++ct) {
                int col = cg * 64 + ct * 16 + l15;
                f16x8 bf = *(const f16x8*)&bs[(mat * 256 + col) * KP + quad * 8];
                acc[0][ct] = __builtin_amdgcn_mfma_f32_16x16x32_f16(af0, bf, acc[0][ct], 0, 0, 0);
                acc[1][ct] = __builtin_amdgcn_mfma_f32_16x16x32_f16(af1, bf, acc[1][ct], 0, 0, 0);
            }
        }
    }
    if (row0 < NN) {
        float* dst = mat ? xr : xl;
        #pragma unroll
        for (int s = 0; s < 2; ++s)
            #pragma unroll
            for (int ct = 0; ct < 4; ++ct) {
                int col = cg * 64 + ct * 16 + l15;
                #pragma unroll
                for (int r = 0; r < 4; ++r)
                    dst[(row0 + s * 16 + quad * 4 + r) * F1 + col] = acc[s][ct][r];
            }
    } else if (mat == 0) {
        #pragma unroll
        for (int ct = 0; ct < 4; ++ct) {
            int col = cg * 64 + ct * 16 + l15;
            float bv = b1[col];
            #pragma unroll
            for (int s = 0; s < 2; ++s)
                #pragma unroll
                for (int r = 0; r < 4; ++r)
                    h1h[(row0 + s * 16 + quad * 4 + r) * F1 + col] =
                        (_Float16)eluf(acc[s][ct][r] + bv);
        }
    }
}

// ===== L5: gather layer 1 -> h1h f16 (divide/bias/elu fused) =====
__global__ __launch_bounds__(256) void k_gat1(const int* __restrict__ off,
        const int* __restrict__ srcs4, const float* __restrict__ xl,
        const float* __restrict__ xr, const float* __restrict__ att,
        const float* __restrict__ b1, _Float16* __restrict__ h1h) {
    const int d = blockIdx.x;
    const int t = threadIdx.x;
    const int wv = t >> 6, c = t & 63;
    const int e0 = off[d], e1 = off[d + 1];
    float b[4], at[4], sh[4], acc[4] = {0,0,0,0}, dnl[4] = {0,0,0,0};
    #pragma unroll
    for (int k = 0; k < 4; ++k) {
        b[k]  = xr[d * F1 + c + 64 * k];
        at[k] = att[c + 64 * k];
        sh[k] = lrelu(xl[d * F1 + c + 64 * k] + b[k]) * at[k];
    }
    #pragma unroll
    for (int o = 32; o; o >>= 1) {
        #pragma unroll
        for (int k = 0; k < 4; ++k) sh[k] += __shfl_xor(sh[k], o, 64);
    }
    for (int e = e0 + wv; e < e1; e += 4) {
        int s = srcs4[e];
        float a[4], p[4];
        #pragma unroll
        for (int k = 0; k < 4; ++k) {
            a[k] = xl[s * F1 + c + 64 * k];
            p[k] = lrelu(a[k] + b[k]) * at[k];
        }
        #pragma unroll
        for (int o = 32; o; o >>= 1) {
            #pragma unroll
            for (int k = 0; k < 4; ++k) p[k] += __shfl_xor(p[k], o, 64);
        }
        #pragma unroll
        for (int k = 0; k < 4; ++k) {
            float w = 8.0f * __expf(p[k] - sh[k]);
            dnl[k] += w;
            acc[k] = fmaf(w, a[k], acc[k]);
        }
    }
    __shared__ float lacc[4][F1];
    __shared__ float ldn[4][4];
    #pragma unroll
    for (int k = 0; k < 4; ++k) lacc[wv][c + 64 * k] = acc[k];
    if (c < 4) ldn[wv][c] = dnl[c];
    __syncthreads();
    int f = t, h = t >> 6;
    float tot = xl[d * F1 + f] + lacc[0][f] + lacc[1][f] + lacc[2][f] + lacc[3][f];
    float dnf = 1.0f + ldn[0][h] + ldn[1][h] + ldn[2][h] + ldn[3][h];
    h1h[d * F1 + f] = (_Float16)eluf(tot / (dnf + 1e-16f) + b1[f]);
}

// ===== L6: layer-2 dual MFMA GEMM, A read from global f16 =====
// rows<NN -> xl2/xr2; rows>=NN -> acc2 = aL (final, dn=1)
__global__ __launch_bounds__(512) void gm2(const _Float16* __restrict__ Ah,
        const _Float16* __restrict__ BTl, const _Float16* __restrict__ BTr,
        float* __restrict__ xl2, float* __restrict__ xr2, float* __restrict__ acc2) {
    alignas(16) __shared__ _Float16 bs[2 * 128 * KP];  // 20 KB
    const int t = threadIdx.x;
    const int wave = t >> 6, lane = t & 63;
    const int quad = lane >> 4, l15 = lane & 15;
    const int mat = wave >> 2, cg = wave & 3;
    const int row0 = blockIdx.x * 32;
    const int nmats = (row0 < NN) ? 2 : 1;
    f32x4 acc[2][2];
    #pragma unroll
    for (int s = 0; s < 2; ++s)
        #pragma unroll
        for (int c = 0; c < 2; ++c) acc[s][c] = (f32x4){0,0,0,0};
    for (int kt = 0; kt < F1; kt += 32) {
        if (kt) __syncthreads();
        for (int it = 0; it < nmats; ++it) {  // nmats x 128 cols x 4 chunks = nmats*512
            int idx = t + it * 512;
            int m = idx >> 9, rem = idx & 511;
            int col = rem >> 2, j = rem & 3;
            const _Float16* src = (m ? BTr : BTl) + col * F1 + kt + j * 8;
            *(f16x8*)&bs[(m * 128 + col) * KP + j * 8] = *(const f16x8*)src;
        }
        __syncthreads();
        if (mat < nmats) {
            f16x8 af0 = *(const f16x8*)&Ah[(row0 + l15) * F1 + kt + quad * 8];
            f16x8 af1 = *(const f16x8*)&Ah[(row0 + 16 + l15) * F1 + kt + quad * 8];
            #pragma unroll
            for (int ct = 0; ct < 2; ++ct) {
                int col = cg * 32 + ct * 16 + l15;
                f16x8 bf = *(const f16x8*)&bs[(mat * 128 + col) * KP + quad * 8];
                acc[0][ct] = __builtin_amdgcn_mfma_f32_16x16x32_f16(af0, bf, acc[0][ct], 0, 0, 0);
                acc[1][ct] = __builtin_amdgcn_mfma_f32_16x16x32_f16(af1, bf, acc[1][ct], 0, 0, 0);
            }
        }
    }
    if (row0 < NN) {
        float* dst = mat ? xr2 : xl2;
        #pragma unroll
        for (int s = 0; s < 2; ++s)
            #pragma unroll
            for (int ct = 0; ct < 2; ++ct) {
                int col = cg * 32 + ct * 16 + l15;
                #pragma unroll
                for (int r = 0; r < 4; ++r)
                    dst[(row0 + s * 16 + quad * 4 + r) * F2 + col] = acc[s][ct][r];
            }
    } else if (mat == 0) {
        #pragma unroll
        for (int s = 0; s < 2; ++s)
            #pragma unroll
            for (int ct = 0; ct < 2; ++ct) {
                int col = cg * 32 + ct * 16 + l15;
                #pragma unroll
                for (int r = 0; r < 4; ++r)
                    acc2[(row0 + s * 16 + quad * 4 + r) * F2 + col] = acc[s][ct][r];
            }
    }
}

// ===== L7: gather layer 2 -> acc2 final (divide fused) =====
__global__ __launch_bounds__(256) void k_gat2(const int* __restrict__ off,
        const int* __restrict__ srcs4, const float* __restrict__ xl,
        const float* __restrict__ xr, const float* __restrict__ att,
        float* __restrict__ acc2) {
    const int d = blockIdx.x;
    const int t = threadIdx.x;
    const int wv = t >> 6, c = t & 63;
    const int e0 = off[d], e1 = off[d + 1];
    float b0 = xr[d * F2 + c], b1v = xr[d * F2 + c + 64];
    float at0 = att[c], at1 = att[c + 64];
    float sh = lrelu(xl[d * F2 + c] + b0) * at0 + lrelu(xl[d * F2 + c + 64] + b1v) * at1;
    #pragma unroll
    for (int o = 32; o; o >>= 1) sh += __shfl_xor(sh, o, 64);
    float acc0 = 0.f, acc1v = 0.f, dnl = 0.f;
    for (int e = e0 + wv; e < e1; e += 4) {
        int s = srcs4[e];
        float a0 = xl[s * F2 + c], a1 = xl[s * F2 + c + 64];
        float p = lrelu(a0 + b0) * at0 + lrelu(a1 + b1v) * at1;
        #pragma unroll
        for (int o = 32; o; o >>= 1) p += __shfl_xor(p, o, 64);
        float w = 8.0f * __expf(p - sh);
        dnl += w;
        acc0 = fmaf(w, a0, acc0);
        acc1v = fmaf(w, a1, acc1v);
    }
    __shared__ float lacc[4][F2];
    __shared__ float ldn[4];
    lacc[wv][c] = acc0;
    lacc[wv][c + 64] = acc1v;
    if (c == 0) ldn[wv] = dnl;
    __syncthreads();
    if (t < F2) {
        int f = t;
        float dnf = 1.0f + ldn[0] + ldn[1] + ldn[2] + ldn[3] + 1e-16f;
        acc2[d * F2 + f] = (xl[d * F2 + f] + lacc[0][f] + lacc[1][f] + lacc[2][f] + lacc[3][f]) / dnf;
    }
}

// ===== L8: batched mean =====
__global__ __launch_bounds__(128) void k_out(const float* __restrict__ accum,
        const float* __restrict__ b2, float* __restrict__ out) {
    int b = blockIdx.x, chunk = blockIdx.y;
    int c = threadIdx.x;
    float acc = 0.f;
    int n0 = b * NN + chunk * 32;
    for (int i = 0; i < 32; ++i)
        acc += accum[(n0 + i) * F2 + c];
    float val = acc * (1.0f / NN);
    if (chunk == 0) val += b2[c];
    atomicAdd(&out[b * F2 + c], val);
}

extern "C" void kernel_launch(void* const* d_in, const int* in_sizes, int n_in,
                              void* d_out, int out_size, void* d_ws, size_t ws_size,
                              hipStream_t stream) {
    const float* in   = (const float*)d_in[0];
    const int*   ei   = (const int*)d_in[1];
    const float* Wt   = (const float*)d_in[2];
    const float* bt   = (const float*)d_in[3];
    const float* Wl1  = (const float*)d_in[4];
    const float* Wr1  = (const float*)d_in[5];
    const float* att1 = (const float*)d_in[6];
    const float* b1   = (const float*)d_in[7];
    const float* Wl2  = (const float*)d_in[8];
    const float* Wr2  = (const float*)d_in[9];
    const float* att2 = (const float*)d_in[10];
    const float* b2   = (const float*)d_in[11];
    float* out = (float*)d_out;

    float* ws = (float*)d_ws;
    _Float16* xTh = (_Float16*)ws;          // N*128 f16 (4 MB)
    _Float16* xh  = xTh + N * 128;          // N*CIN f16 (4 MB)
    _Float16* h1h = xh + N * CIN;           // N*F1 f16  (8 MB)
    float* xl1  = (float*)(h1h + N * F1);   // NN*F1 (2 MB)
    float* xr1  = xl1 + NN * F1;            // NN*F1
    float* xl2  = xr1 + NN * F1;            // NN*F2
    float* xr2  = xl2 + NN * F2;            // NN*F2
    float* acc2 = xr2 + NN * F2;            // N*F2 (8 MB)
    _Float16* Tt  = (_Float16*)(acc2 + N * F2);  // 128*128
    _Float16* T1l = Tt + 128 * 128;         // 256*128
    _Float16* T1r = T1l + 256 * 128;
    _Float16* T2l = T1r + 256 * 128;        // 128*256
    _Float16* T2r = T2l + 128 * 256;
    int* off  = (int*)(T2r + 128 * 256);    // NN+1
    int* cur  = off + (NN + 1);             // NN
    int* srcs = cur + NN;                   // E

    k_prep<<<dim3(32, 6), 256, 0, stream>>>(Wt, Wl1, Wr1, Wl2, Wr2,
                                            Tt, T1l, T1r, T2l, T2r, cur, out);
    k_cvt_hist<<<dim3(128, 9), 256, 0, stream>>>(in, xTh, ei, cur);
    k_scan_gmt<<<513, 256, 0, stream>>>(off, cur, xTh, Tt, bt, xh);
    k_scat_gm1<<<576, 512, 0, stream>>>(ei, cur, srcs, xh, T1l, T1r, b1, xl1, xr1, h1h);
    k_gat1<<<NN, 256, 0, stream>>>(off, srcs, xl1, xr1, att1, b1, h1h);
    gm2<<<512, 512, 0, stream>>>(h1h, T2l, T2r, xl2, xr2, acc2);
    k_gat2<<<NN, 256, 0, stream>>>(off, srcs, xl2, xr2, att2, acc2);
    k_out<<<dim3(BSZ, 64), 128, 0, stream>>>(acc2, b2, out);
}